// Round 1
// baseline (489.329 us; speedup 1.0000x reference)
//
#include <hip/hip_runtime.h>

#define NCRD 4096       // N coords rows
#define NROW 8192       // 2N network rows
#define HDIM 256        // hidden width (= 2F)
#define NT   16         // rows per block
#define KC   32         // k-chunk staged in LDS
#define XS   20         // xt row stride in floats (16B-aligned, conflict-mitigating)

static __device__ __forceinline__ float sinrev(float t) {
    // sin(2*pi*t): v_fract range-reduce then v_sin (input in revolutions)
    return __builtin_amdgcn_sinf(__builtin_amdgcn_fractf(t));
}
static __device__ __forceinline__ float cosrev(float t) {
    return __builtin_amdgcn_cosf(__builtin_amdgcn_fractf(t));
}

// ---------------- prep: transpose+scale weights to [k][h], *1/(2pi) -------
__global__ void prep_kernel(const float* __restrict__ w0,
                            const float* __restrict__ ws,
                            const float* __restrict__ wlast,
                            const float* __restrict__ w1,
                            float* __restrict__ Wt)
{
    __shared__ float tile[32][33];
    int l  = blockIdx.x;   // layer 0..8
    int ti = blockIdx.y;   // h tile
    int tj = blockIdx.z;   // k tile
    const float* src;
    switch (l) {
        case 0: src = w0;            break;
        case 1: src = w1;            break;
        case 2: src = ws;            break;
        case 3: src = w1 + 65536;    break;
        case 4: src = ws + 65536;    break;
        case 5: src = w1 + 2*65536;  break;
        case 6: src = ws + 2*65536;  break;
        case 7: src = w1 + 3*65536;  break;
        default: src = wlast;        break;
    }
    int tx = threadIdx.x & 31, ty = threadIdx.x >> 5;   // 32 x 8
    #pragma unroll
    for (int r = 0; r < 4; ++r) {
        int h = ti*32 + ty + r*8;
        tile[ty + r*8][tx] = src[h*256 + tj*32 + tx];
    }
    __syncthreads();
    const float s = 0.15915494309189535f;   // 1/(2*pi)
    float* dst = Wt + l*65536;
    #pragma unroll
    for (int r = 0; r < 4; ++r) {
        int k = tj*32 + ty + r*8;
        dst[k*256 + ti*32 + tx] = tile[tx][ty + r*8] * s;
    }
}

// ---------------- misc: scale biases, copy coords passthrough -------------
__global__ void misc_kernel(const float* __restrict__ coords,
                            const float* __restrict__ b1,
                            float* __restrict__ b1s,
                            float* __restrict__ out)
{
    int i = blockIdx.x*256 + threadIdx.x;
    if (i < 1024)  b1s[i] = b1[i] * 0.15915494309189535f;
    if (i < NCRD*6) out[NROW*HDIM + i] = coords[i];
}

// ---------------- one layer pass ------------------------------------------
template<bool GEMM, bool LAST>
static __device__ __forceinline__ void layer_pass(
    const float* __restrict__ wsrc,   // transposed scaled weights [256][256]
    const float* __restrict__ bias,   // scaled bias (GEMM only)
    float* __restrict__ outg,         // global out (LAST only)
    float* xt, float* wl,
    int tid, int hb, int nb, int n0)
{
    float acc[4][4];
    if (GEMM) {
        float4 b4 = *(const float4*)(bias + hb);
        #pragma unroll
        for (int i = 0; i < 4; ++i) {
            acc[i][0] = b4.x; acc[i][1] = b4.y; acc[i][2] = b4.z; acc[i][3] = b4.w;
        }
    } else {
        #pragma unroll
        for (int i = 0; i < 4; ++i)
            #pragma unroll
            for (int j = 0; j < 4; ++j) acc[i][j] = 0.f;
    }

    for (int kc = 0; kc < HDIM/KC; ++kc) {
        __syncthreads();                         // protect wl reuse
        const float4* g  = (const float4*)(wsrc + kc*KC*HDIM);
        float4*       w4 = (float4*)wl;
        #pragma unroll
        for (int i = 0; i < 8; ++i)              // 32KB chunk, coalesced
            w4[i*256 + tid] = g[i*256 + tid];
        __syncthreads();

        #pragma unroll 4
        for (int k = 0; k < KC; ++k) {
            float4 xv = *(const float4*)(xt + (kc*KC + k)*XS + nb);  // broadcast
            float4 wv = *(const float4*)(wl + k*HDIM + hb);          // conflict-free
            float xa[4] = {xv.x, xv.y, xv.z, xv.w};
            float wa[4] = {wv.x, wv.y, wv.z, wv.w};
            #pragma unroll
            for (int i = 0; i < 4; ++i)
                #pragma unroll
                for (int j = 0; j < 4; ++j) {
                    if (GEMM) acc[i][j] = fmaf(xa[i], wa[j], acc[i][j]);
                    else      acc[i][j] += sinrev(xa[i] * wa[j]);
                }
        }
    }
    __syncthreads();                             // all xt reads done

    if (LAST) {
        #pragma unroll
        for (int i = 0; i < 4; ++i) {
            float4 v = make_float4(acc[i][0], acc[i][1], acc[i][2], acc[i][3]);
            *(float4*)(outg + (size_t)(n0 + nb + i)*HDIM + hb) = v;
        }
    } else {
        #pragma unroll
        for (int j = 0; j < 4; ++j) {
            float4 v;
            if (GEMM) v = make_float4(sinrev(acc[0][j]), sinrev(acc[1][j]),
                                      sinrev(acc[2][j]), sinrev(acc[3][j]));
            else      v = make_float4(acc[0][j], acc[1][j], acc[2][j], acc[3][j]);
            *(float4*)(xt + (hb + j)*XS + nb) = v;   // next layer's k-major input
        }
    }
}

// ---------------- fused network kernel ------------------------------------
__global__ __launch_bounds__(256)
void net_kernel(const float* __restrict__ coords,
                const float* __restrict__ Bm,
                const float* __restrict__ Wt,
                const float* __restrict__ b1s,
                float* __restrict__ out)
{
    __shared__ __align__(16) float xt[HDIM * XS];   // activations, [k][n]
    __shared__ __align__(16) float wl[KC * HDIM];   // weight chunk, [k][h]
    __shared__ float cb[NT * 3];

    int tid = threadIdx.x;
    int n0  = blockIdx.x * NT;
    int hb  = (tid & 63) * 4;    // 4 h's per thread
    int nb  = (tid >> 6) * 4;    // 4 n's per thread (wave-uniform)

    // ---- stage A: fourier features -> xt ----
    if (tid < NT*3) {
        int n = tid / 3, d = tid - n*3;
        int nv = n0 + n;
        cb[tid] = (nv < NCRD) ? coords[nv*6 + d] : coords[(nv - NCRD)*6 + 3 + d];
    }
    __syncthreads();
    {
        int f = tid & 127;
        float bx = Bm[f], by = Bm[128 + f], bz = Bm[256 + f];
        bool iscos = tid >= 128;
        float vals[NT];
        #pragma unroll
        for (int n = 0; n < NT; ++n) {
            float t = cb[n*3]*bx + cb[n*3+1]*by + cb[n*3+2]*bz;  // 2pi cancels
            vals[n] = iscos ? cosrev(t) : sinrev(t);
        }
        #pragma unroll
        for (int n = 0; n < NT; n += 4)
            *(float4*)(xt + tid*XS + n) =
                make_float4(vals[n], vals[n+1], vals[n+2], vals[n+3]);
    }
    // (layer 0's first chunk barrier orders these writes before reads)

    // ---- 9 layers ----
    layer_pass<false,false>(Wt + 0*65536, nullptr,    nullptr, xt, wl, tid, hb, nb, n0);
    layer_pass<true ,false>(Wt + 1*65536, b1s + 0,    nullptr, xt, wl, tid, hb, nb, n0);
    layer_pass<false,false>(Wt + 2*65536, nullptr,    nullptr, xt, wl, tid, hb, nb, n0);
    layer_pass<true ,false>(Wt + 3*65536, b1s + 256,  nullptr, xt, wl, tid, hb, nb, n0);
    layer_pass<false,false>(Wt + 4*65536, nullptr,    nullptr, xt, wl, tid, hb, nb, n0);
    layer_pass<true ,false>(Wt + 5*65536, b1s + 512,  nullptr, xt, wl, tid, hb, nb, n0);
    layer_pass<false,false>(Wt + 6*65536, nullptr,    nullptr, xt, wl, tid, hb, nb, n0);
    layer_pass<true ,false>(Wt + 7*65536, b1s + 768,  nullptr, xt, wl, tid, hb, nb, n0);
    layer_pass<false,true >(Wt + 8*65536, nullptr,    out,     xt, wl, tid, hb, nb, n0);
}

// ---------------- launch ---------------------------------------------------
extern "C" void kernel_launch(void* const* d_in, const int* in_sizes, int n_in,
                              void* d_out, int out_size, void* d_ws, size_t ws_size,
                              hipStream_t stream)
{
    const float* coords = (const float*)d_in[0];
    const float* Bm     = (const float*)d_in[1];
    const float* w0     = (const float*)d_in[2];
    const float* ws     = (const float*)d_in[3];
    const float* wlast  = (const float*)d_in[4];
    const float* w1     = (const float*)d_in[5];
    const float* b1     = (const float*)d_in[6];
    float* out = (float*)d_out;

    float* Wt  = (float*)d_ws;            // 9 * 256*256 floats
    float* b1s = Wt + 9*65536;            // 4*256 floats

    dim3 pg(9, 8, 8);
    prep_kernel<<<pg, 256, 0, stream>>>(w0, ws, wlast, w1, Wt);
    misc_kernel<<<96, 256, 0, stream>>>(coords, b1, b1s, out);
    net_kernel<<<NROW/NT, 256, 0, stream>>>(coords, Bm, Wt, b1s, out);
}

// Round 2
// 445.344 us; speedup vs baseline: 1.0988x; 1.0988x over previous
//
#include <hip/hip_runtime.h>

#define NCRD 4096       // N coords rows
#define NROW 8192       // 2N network rows
#define HDIM 256        // hidden width (= 2F)
#define NT   16         // rows per block
#define XS   20         // xt row stride in floats (16B-aligned)

static __device__ __forceinline__ float sinrev(float t) {
    // sin(2*pi*t), |t| can be large: fract range-reduce then v_sin
    return __builtin_amdgcn_sinf(__builtin_amdgcn_fractf(t));
}
static __device__ __forceinline__ float cosrev(float t) {
    return __builtin_amdgcn_cosf(__builtin_amdgcn_fractf(t));
}
static __device__ __forceinline__ float sinrev_small(float t) {
    // |t| < ~0.15 revolutions: gfx9+ v_sin needs no range reduction
    return __builtin_amdgcn_sinf(t);
}

// ---------------- prep: transpose+scale weights to [k][h], *1/(2pi) -------
__global__ void prep_kernel(const float* __restrict__ w0,
                            const float* __restrict__ ws,
                            const float* __restrict__ wlast,
                            const float* __restrict__ w1,
                            float* __restrict__ Wt)
{
    __shared__ float tile[32][33];
    int l  = blockIdx.x;   // layer 0..8
    int ti = blockIdx.y;   // h tile
    int tj = blockIdx.z;   // k tile
    const float* src;
    switch (l) {
        case 0: src = w0;            break;
        case 1: src = w1;            break;
        case 2: src = ws;            break;
        case 3: src = w1 + 65536;    break;
        case 4: src = ws + 65536;    break;
        case 5: src = w1 + 2*65536;  break;
        case 6: src = ws + 2*65536;  break;
        case 7: src = w1 + 3*65536;  break;
        default: src = wlast;        break;
    }
    int tx = threadIdx.x & 31, ty = threadIdx.x >> 5;   // 32 x 8
    #pragma unroll
    for (int r = 0; r < 4; ++r) {
        int h = ti*32 + ty + r*8;
        tile[ty + r*8][tx] = src[h*256 + tj*32 + tx];
    }
    __syncthreads();
    const float s = 0.15915494309189535f;   // 1/(2*pi)
    float* dst = Wt + l*65536;
    #pragma unroll
    for (int r = 0; r < 4; ++r) {
        int k = tj*32 + ty + r*8;
        dst[k*256 + ti*32 + tx] = tile[tx][ty + r*8] * s;
    }
}

// ---------------- misc: scale biases, copy coords passthrough -------------
__global__ void misc_kernel(const float* __restrict__ coords,
                            const float* __restrict__ b1,
                            float* __restrict__ b1s,
                            float* __restrict__ out)
{
    int i = blockIdx.x*256 + threadIdx.x;
    if (i < 1024)  b1s[i] = b1[i] * 0.15915494309189535f;
    if (i < NCRD*6) out[NROW*HDIM + i] = coords[i];
}

// ---------------- one layer pass ------------------------------------------
// Weights read straight from global (L1/L2-resident, wave-coalesced 1KB/instr,
// identical addresses across the 4 waves -> L1 reuse). No LDS weight staging,
// so only 2 barriers per layer.
template<bool GEMM, bool LAST>
static __device__ __forceinline__ void layer_pass(
    const float* __restrict__ wsrc,   // transposed scaled weights [256][256]
    const float* __restrict__ bias,   // scaled bias (GEMM only)
    float* __restrict__ outg,         // global out (LAST only)
    float* xt,
    int tid, int hb, int nb, int n0)
{
    float2 acc[4][2];                 // [n][h-pair], packed-f32 friendly
    if (GEMM) {
        float4 b4 = *(const float4*)(bias + hb);
        #pragma unroll
        for (int i = 0; i < 4; ++i) {
            acc[i][0] = make_float2(b4.x, b4.y);
            acc[i][1] = make_float2(b4.z, b4.w);
        }
    } else {
        #pragma unroll
        for (int i = 0; i < 4; ++i) {
            acc[i][0] = make_float2(0.f, 0.f);
            acc[i][1] = make_float2(0.f, 0.f);
        }
    }

    __syncthreads();                  // previous layer's xt writes visible

    const float4* wp = (const float4*)wsrc + (hb >> 2);
    #pragma unroll 4
    for (int k = 0; k < HDIM; ++k) {
        float4 wv = wp[k * (HDIM/4)];                       // global, L1/L2 hit
        float4 xv = *(const float4*)(xt + k*XS + nb);       // LDS broadcast
        float xa[4] = {xv.x, xv.y, xv.z, xv.w};
        float2 w2[2] = { make_float2(wv.x, wv.y), make_float2(wv.z, wv.w) };
        #pragma unroll
        for (int i = 0; i < 4; ++i) {
            #pragma unroll
            for (int jp = 0; jp < 2; ++jp) {
                if (GEMM) {
                    acc[i][jp].x = fmaf(xa[i], w2[jp].x, acc[i][jp].x);
                    acc[i][jp].y = fmaf(xa[i], w2[jp].y, acc[i][jp].y);
                } else {
                    float tx = xa[i] * w2[jp].x;            // pk_mul pair
                    float ty = xa[i] * w2[jp].y;
                    float sx = sinrev_small(tx);            // |arg| < 0.15 rev
                    float sy = sinrev_small(ty);
                    acc[i][jp].x += sx;                     // pk_add pair
                    acc[i][jp].y += sy;
                }
            }
        }
    }
    __syncthreads();                  // all xt reads done before overwrite

    if (LAST) {
        #pragma unroll
        for (int i = 0; i < 4; ++i) {
            float4 v = make_float4(acc[i][0].x, acc[i][0].y,
                                   acc[i][1].x, acc[i][1].y);
            *(float4*)(outg + (size_t)(n0 + nb + i)*HDIM + hb) = v;
        }
    } else {
        #pragma unroll
        for (int j = 0; j < 4; ++j) {
            int jp = j >> 1;
            float a0 = (j & 1) ? acc[0][jp].y : acc[0][jp].x;
            float a1 = (j & 1) ? acc[1][jp].y : acc[1][jp].x;
            float a2 = (j & 1) ? acc[2][jp].y : acc[2][jp].x;
            float a3 = (j & 1) ? acc[3][jp].y : acc[3][jp].x;
            float4 v;
            if (GEMM) v = make_float4(sinrev(a0), sinrev(a1),
                                      sinrev(a2), sinrev(a3));
            else      v = make_float4(a0, a1, a2, a3);
            *(float4*)(xt + (hb + j)*XS + nb) = v;   // next layer's k-major input
        }
    }
}

// ---------------- fused network kernel ------------------------------------
__global__ __launch_bounds__(256)
void net_kernel(const float* __restrict__ coords,
                const float* __restrict__ Bm,
                const float* __restrict__ Wt,
                const float* __restrict__ b1s,
                float* __restrict__ out)
{
    __shared__ __align__(16) float xt[HDIM * XS];   // activations, [k][n]
    __shared__ float cb[NT * 3];

    int tid = threadIdx.x;
    int n0  = blockIdx.x * NT;
    int hb  = (tid & 63) * 4;    // 4 h's per thread
    int nb  = (tid >> 6) * 4;    // 4 n's per thread (wave-uniform)

    // ---- stage A: fourier features -> xt ----
    if (tid < NT*3) {
        int n = tid / 3, d = tid - n*3;
        int nv = n0 + n;
        cb[tid] = (nv < NCRD) ? coords[nv*6 + d] : coords[(nv - NCRD)*6 + 3 + d];
    }
    __syncthreads();
    {
        int f = tid & 127;
        float bx = Bm[f], by = Bm[128 + f], bz = Bm[256 + f];
        bool iscos = tid >= 128;
        float vals[NT];
        #pragma unroll
        for (int n = 0; n < NT; ++n) {
            float t = cb[n*3]*bx + cb[n*3+1]*by + cb[n*3+2]*bz;  // 2pi cancels
            vals[n] = iscos ? cosrev(t) : sinrev(t);             // large args: fract
        }
        #pragma unroll
        for (int n = 0; n < NT; n += 4)
            *(float4*)(xt + tid*XS + n) =
                make_float4(vals[n], vals[n+1], vals[n+2], vals[n+3]);
    }
    // (layer 0's entry barrier orders these writes before reads)

    // ---- 9 layers ----
    layer_pass<false,false>(Wt + 0*65536, nullptr,    nullptr, xt, tid, hb, nb, n0);
    layer_pass<true ,false>(Wt + 1*65536, b1s + 0,    nullptr, xt, tid, hb, nb, n0);
    layer_pass<false,false>(Wt + 2*65536, nullptr,    nullptr, xt, tid, hb, nb, n0);
    layer_pass<true ,false>(Wt + 3*65536, b1s + 256,  nullptr, xt, tid, hb, nb, n0);
    layer_pass<false,false>(Wt + 4*65536, nullptr,    nullptr, xt, tid, hb, nb, n0);
    layer_pass<true ,false>(Wt + 5*65536, b1s + 512,  nullptr, xt, tid, hb, nb, n0);
    layer_pass<false,false>(Wt + 6*65536, nullptr,    nullptr, xt, tid, hb, nb, n0);
    layer_pass<true ,false>(Wt + 7*65536, b1s + 768,  nullptr, xt, tid, hb, nb, n0);
    layer_pass<false,true >(Wt + 8*65536, nullptr,    out,     xt, tid, hb, nb, n0);
}

// ---------------- launch ---------------------------------------------------
extern "C" void kernel_launch(void* const* d_in, const int* in_sizes, int n_in,
                              void* d_out, int out_size, void* d_ws, size_t ws_size,
                              hipStream_t stream)
{
    const float* coords = (const float*)d_in[0];
    const float* Bm     = (const float*)d_in[1];
    const float* w0     = (const float*)d_in[2];
    const float* ws     = (const float*)d_in[3];
    const float* wlast  = (const float*)d_in[4];
    const float* w1     = (const float*)d_in[5];
    const float* b1     = (const float*)d_in[6];
    float* out = (float*)d_out;

    float* Wt  = (float*)d_ws;            // 9 * 256*256 floats
    float* b1s = Wt + 9*65536;            // 4*256 floats

    dim3 pg(9, 8, 8);
    prep_kernel<<<pg, 256, 0, stream>>>(w0, ws, wlast, w1, Wt);
    misc_kernel<<<96, 256, 0, stream>>>(coords, b1, b1s, out);
    net_kernel<<<NROW/NT, 256, 0, stream>>>(coords, Bm, Wt, b1s, out);
}

// Round 4
// 424.162 us; speedup vs baseline: 1.1536x; 1.0499x over previous
//
#include <hip/hip_runtime.h>

#define NCRD 4096       // N coords rows
#define NROW 8192       // 2N network rows
#define HDIM 256        // hidden width (= 2F)
#define NT   8          // rows per block (1024 blocks -> 4 blocks/CU)
#define XS   12         // xt row stride in floats (16B-aligned)

static __device__ __forceinline__ float sinrev(float t) {
    // sin(2*pi*t), |t| can be large: fract range-reduce then v_sin
    return __builtin_amdgcn_sinf(__builtin_amdgcn_fractf(t));
}
static __device__ __forceinline__ float cosrev(float t) {
    return __builtin_amdgcn_cosf(__builtin_amdgcn_fractf(t));
}
static __device__ __forceinline__ float sinrev_small(float t) {
    // |t| < ~0.15 revolutions: gfx9+ v_sin needs no range reduction
    return __builtin_amdgcn_sinf(t);
}

// ---- prep: transpose+scale weights to [k][h] * 1/(2pi); l==9: bias+coords --
__global__ void prep_kernel(const float* __restrict__ w0,
                            const float* __restrict__ ws,
                            const float* __restrict__ wlast,
                            const float* __restrict__ w1,
                            const float* __restrict__ coords,
                            const float* __restrict__ b1,
                            float* __restrict__ Wt,
                            float* __restrict__ b1s,
                            float* __restrict__ out)
{
    __shared__ float tile[32][33];
    int l  = blockIdx.x;   // 0..8 = layer transpose; 9 = misc
    int ti = blockIdx.y;
    int tj = blockIdx.z;
    const float s = 0.15915494309189535f;   // 1/(2*pi)

    if (l == 9) {
        int base = (ti*8 + tj)*256 + threadIdx.x;       // 0..16383
        if (base < 1024) b1s[base] = b1[base] * s;
        for (int i = base; i < NCRD*6; i += 16384)       // full 24576 coords
            out[NROW*HDIM + i] = coords[i];
        return;
    }

    const float* src;
    switch (l) {
        case 0: src = w0;            break;
        case 1: src = w1;            break;
        case 2: src = ws;            break;
        case 3: src = w1 + 65536;    break;
        case 4: src = ws + 65536;    break;
        case 5: src = w1 + 2*65536;  break;
        case 6: src = ws + 2*65536;  break;
        case 7: src = w1 + 3*65536;  break;
        default: src = wlast;        break;
    }
    int tx = threadIdx.x & 31, ty = threadIdx.x >> 5;   // 32 x 8
    #pragma unroll
    for (int r = 0; r < 4; ++r) {
        int h = ti*32 + ty + r*8;
        tile[ty + r*8][tx] = src[h*256 + tj*32 + tx];
    }
    __syncthreads();
    float* dst = Wt + l*65536;
    #pragma unroll
    for (int r = 0; r < 4; ++r) {
        int k = tj*32 + ty + r*8;
        dst[k*256 + ti*32 + tx] = tile[tx][ty + r*8] * s;
    }
}

// ---------------- one layer pass ------------------------------------------
// Weights read straight from global (L1/L2-resident, wave-coalesced 1KB/instr,
// identical addresses across waves/blocks on a CU -> cache reuse).
// 2 barriers per layer. Each thread: 2 rows (nb..nb+1) x 4 cols (hb..hb+3).
template<bool GEMM, bool LAST>
static __device__ __forceinline__ void layer_pass(
    const float* __restrict__ wsrc,   // transposed scaled weights [256][256]
    const float* __restrict__ bias,   // scaled bias (GEMM only)
    float* __restrict__ outg,         // global out (LAST only)
    float* xt,
    int tid, int hb, int nb, int n0)
{
    float2 acc[2][2];                 // [n][h-pair]
    if (GEMM) {
        float4 b4 = *(const float4*)(bias + hb);
        #pragma unroll
        for (int i = 0; i < 2; ++i) {
            acc[i][0] = make_float2(b4.x, b4.y);
            acc[i][1] = make_float2(b4.z, b4.w);
        }
    } else {
        #pragma unroll
        for (int i = 0; i < 2; ++i) {
            acc[i][0] = make_float2(0.f, 0.f);
            acc[i][1] = make_float2(0.f, 0.f);
        }
    }

    __syncthreads();                  // previous layer's xt writes visible

    const float4* wp = (const float4*)wsrc + (hb >> 2);
    #pragma unroll 4
    for (int k = 0; k < HDIM; ++k) {
        float4 wv = wp[k * (HDIM/4)];                       // global, L1/L2 hit
        float2 xv = *(const float2*)(xt + k*XS + nb);       // LDS broadcast
        float xa[2] = {xv.x, xv.y};
        float2 w2[2] = { make_float2(wv.x, wv.y), make_float2(wv.z, wv.w) };
        #pragma unroll
        for (int i = 0; i < 2; ++i) {
            #pragma unroll
            for (int jp = 0; jp < 2; ++jp) {
                if (GEMM) {
                    acc[i][jp].x = fmaf(xa[i], w2[jp].x, acc[i][jp].x);
                    acc[i][jp].y = fmaf(xa[i], w2[jp].y, acc[i][jp].y);
                } else {
                    float tx = xa[i] * w2[jp].x;
                    float ty = xa[i] * w2[jp].y;
                    float sx = sinrev_small(tx);            // |arg| < 0.15 rev
                    float sy = sinrev_small(ty);
                    acc[i][jp].x += sx;
                    acc[i][jp].y += sy;
                }
            }
        }
    }
    __syncthreads();                  // all xt reads done before overwrite

    if (LAST) {
        #pragma unroll
        for (int i = 0; i < 2; ++i) {
            float4 v = make_float4(acc[i][0].x, acc[i][0].y,
                                   acc[i][1].x, acc[i][1].y);
            *(float4*)(outg + (size_t)(n0 + nb + i)*HDIM + hb) = v;
        }
    } else {
        #pragma unroll
        for (int j = 0; j < 4; ++j) {
            int jp = j >> 1;
            float a0 = (j & 1) ? acc[0][jp].y : acc[0][jp].x;
            float a1 = (j & 1) ? acc[1][jp].y : acc[1][jp].x;
            float2 v;
            if (GEMM) v = make_float2(sinrev(a0), sinrev(a1));
            else      v = make_float2(a0, a1);
            *(float2*)(xt + (hb + j)*XS + nb) = v;   // next layer's k-major input
        }
    }
}

// ---------------- fused network kernel ------------------------------------
__global__ __launch_bounds__(256)
void net_kernel(const float* __restrict__ coords,
                const float* __restrict__ Bm,
                const float* __restrict__ Wt,
                const float* __restrict__ b1s,
                float* __restrict__ out)
{
    __shared__ __align__(16) float xt[HDIM * XS];   // activations, [k][n]
    __shared__ float cb[NT * 3];

    int tid = threadIdx.x;
    int n0  = blockIdx.x * NT;
    int hb  = (tid & 63) * 4;    // 4 h's per thread
    int nb  = (tid >> 6) * 2;    // 2 n's per thread (wave-uniform)

    // ---- stage A: fourier features -> xt ----
    if (tid < NT*3) {
        int n = tid / 3, d = tid - n*3;
        int nv = n0 + n;
        cb[tid] = (nv < NCRD) ? coords[nv*6 + d] : coords[(nv - NCRD)*6 + 3 + d];
    }
    __syncthreads();
    {
        int f = tid & 127;
        float bx = Bm[f], by = Bm[128 + f], bz = Bm[256 + f];
        bool iscos = tid >= 128;
        float vals[NT];
        #pragma unroll
        for (int n = 0; n < NT; ++n) {
            float t = cb[n*3]*bx + cb[n*3+1]*by + cb[n*3+2]*bz;  // 2pi cancels
            vals[n] = iscos ? cosrev(t) : sinrev(t);             // large args: fract
        }
        #pragma unroll
        for (int n = 0; n < NT; n += 4)
            *(float4*)(xt + tid*XS + n) =
                make_float4(vals[n], vals[n+1], vals[n+2], vals[n+3]);
    }
    // (layer 0's entry barrier orders these writes before reads)

    // ---- 9 layers ----
    layer_pass<false,false>(Wt + 0*65536, nullptr,    nullptr, xt, tid, hb, nb, n0);
    layer_pass<true ,false>(Wt + 1*65536, b1s + 0,    nullptr, xt, tid, hb, nb, n0);
    layer_pass<false,false>(Wt + 2*65536, nullptr,    nullptr, xt, tid, hb, nb, n0);
    layer_pass<true ,false>(Wt + 3*65536, b1s + 256,  nullptr, xt, tid, hb, nb, n0);
    layer_pass<false,false>(Wt + 4*65536, nullptr,    nullptr, xt, tid, hb, nb, n0);
    layer_pass<true ,false>(Wt + 5*65536, b1s + 512,  nullptr, xt, tid, hb, nb, n0);
    layer_pass<false,false>(Wt + 6*65536, nullptr,    nullptr, xt, tid, hb, nb, n0);
    layer_pass<true ,false>(Wt + 7*65536, b1s + 768,  nullptr, xt, tid, hb, nb, n0);
    layer_pass<false,true >(Wt + 8*65536, nullptr,    out,     xt, tid, hb, nb, n0);
}

// ---------------- launch ---------------------------------------------------
extern "C" void kernel_launch(void* const* d_in, const int* in_sizes, int n_in,
                              void* d_out, int out_size, void* d_ws, size_t ws_size,
                              hipStream_t stream)
{
    const float* coords = (const float*)d_in[0];
    const float* Bm     = (const float*)d_in[1];
    const float* w0     = (const float*)d_in[2];
    const float* ws     = (const float*)d_in[3];
    const float* wlast  = (const float*)d_in[4];
    const float* w1     = (const float*)d_in[5];
    const float* b1     = (const float*)d_in[6];
    float* out = (float*)d_out;

    float* Wt  = (float*)d_ws;            // 9 * 256*256 floats
    float* b1s = Wt + 9*65536;            // 4*256 floats

    dim3 pg(10, 8, 8);
    prep_kernel<<<pg, 256, 0, stream>>>(w0, ws, wlast, w1, coords, b1, Wt, b1s, out);
    net_kernel<<<NROW/NT, 256, 0, stream>>>(coords, Bm, Wt, b1s, out);
}

// Round 6
// 149.785 us; speedup vs baseline: 3.2669x; 2.8318x over previous
//
#include <hip/hip_runtime.h>
#include <string.h>

#define NCRD 4096
#define NROW 8192
#define MT   32            // rows per block -> 256 blocks (1/CU)
#define WG_BLOCKS 155648   // total prepped weight size in 16B blocks

typedef __attribute__((ext_vector_type(8))) _Float16 half8;
typedef __attribute__((ext_vector_type(4))) float f32x4;

static __device__ __forceinline__ float sinrev(float t){ return __builtin_amdgcn_sinf(__builtin_amdgcn_fractf(t)); }
static __device__ __forceinline__ float cosrev(float t){ return __builtin_amdgcn_cosf(__builtin_amdgcn_fractf(t)); }
static __device__ __forceinline__ unsigned short f2h(float f){   // RNE f32->fp16
    _Float16 h = (_Float16)f;
    unsigned short u; memcpy(&u, &h, 2); return u;
}

// Weight layout: per layer (base offs[l] in 16B units), per 32-k chunk c,
// per 32-col block q, per 16-col tile t, per lane: 16B = 8 halves =
// B[k = c*32 + (lane>>4)*8 + j][col = q*32 + t*16 + (lane&15)].
// uint4 index: offs[l] + c*1024 + q*128 + t*64 + lane.
static __device__ __forceinline__ size_t widx(int keff, int col) {
    int c  = keff >> 5, j = keff & 7, lq = (keff >> 3) & 3;
    int q  = col >> 5, t = (col >> 4) & 1, lr = col & 15;
    return ((size_t)(c*1024 + q*128 + t*64 + lq*16 + lr))*8 + j;   // in halves
}

// ---- prep: fp16 weights in per-fragment layout; l==9: bias+coords ---------
// Sin layers (0,2,4,6,8): terms {W, -W^3/6, W^5/120}, K=768. GEMM: W/(2pi), K=256.
__global__ void prep_kernel(const float* __restrict__ w0, const float* __restrict__ ws,
                            const float* __restrict__ wlast, const float* __restrict__ w1,
                            const float* __restrict__ coords, const float* __restrict__ b1,
                            unsigned short* __restrict__ Wg, float* __restrict__ b1s,
                            float* __restrict__ out)
{
    int l = blockIdx.x, part = blockIdx.y, t = threadIdx.x;
    const float inv2pi = 0.15915494309189535f;
    if (l == 9) {
        int base = part*256 + t;                       // 0..2047
        for (int i = base; i < 1024;   i += 2048) b1s[i] = b1[i]*inv2pi;
        for (int i = base; i < NCRD*6; i += 2048) out[(size_t)NROW*256 + i] = coords[i];
        return;
    }
    const int offs[9] = {0,24576,32768,57344,65536,90112,98304,122880,131072};
    const float* src; bool sinl;
    switch (l) {
        case 0: src = w0;          sinl = true;  break;
        case 1: src = w1;          sinl = false; break;
        case 2: src = ws;          sinl = true;  break;
        case 3: src = w1+65536;    sinl = false; break;
        case 4: src = ws+65536;    sinl = true;  break;
        case 5: src = w1+2*65536;  sinl = false; break;
        case 6: src = ws+2*65536;  sinl = true;  break;
        case 7: src = w1+3*65536;  sinl = false; break;
        default: src = wlast;      sinl = true;  break;
    }
    unsigned short* dst = Wg + (size_t)offs[l]*8;
    int col = part*32 + (t & 31);
    int k0  = (t >> 5) * 32;
    for (int k = k0; k < k0+32; ++k) {
        float w = src[col*256 + k];
        if (sinl) {
            float w3 = w*w*w;
            dst[widx(      k, col)] = f2h(w);
            dst[widx(256 + k, col)] = f2h(-w3*(1.0f/6.0f));
            dst[widx(512 + k, col)] = f2h(w3*w*w*(1.0f/120.0f));
        } else {
            dst[widx(k, col)] = f2h(w*inv2pi);
        }
    }
}

// ---------------- fused MFMA network kernel --------------------------------
// Weights: global->VGPR coalesced dwordx4 (no LDS staging, no K-loop barriers).
// Activations: LDS fp16, MFMA-A blocked layout [kb][m][k%8]. 2 barriers/layer.
__global__ __launch_bounds__(512)
void net_kernel(const float* __restrict__ coords, const float* __restrict__ Bm,
                const unsigned short* __restrict__ Wg, const float* __restrict__ b1s,
                float* __restrict__ out)
{
    __shared__ unsigned short xa[96*32*8];    // 48KB activations
    __shared__ float cb[MT*3];
    __shared__ float bl[384];

    int tid = threadIdx.x, lane = tid & 63, wv = tid >> 6;
    int lq = lane >> 4, lr = lane & 15;
    int n0 = blockIdx.x * MT;

    // ---- fourier features + powers -> xa ----
    for (int i = tid; i < MT*3; i += 512) {
        int r = i/3, d = i - 3*r, nv = n0 + r;
        cb[i] = (nv < NCRD) ? coords[nv*6 + d] : coords[(nv-NCRD)*6 + 3 + d];
    }
    for (int i = tid; i < 384; i += 512) bl[i] = Bm[i];
    __syncthreads();
    {
        int m = tid & 31, colb = (tid >> 5) * 16;       // 16 cols per thread
        float c0 = cb[m*3], c1 = cb[m*3+1], c2 = cb[m*3+2];
        unsigned short tmp[3][16];
        #pragma unroll
        for (int j = 0; j < 16; ++j) {
            int col = colb + j, f = col & 127;
            float p = c0*bl[f] + c1*bl[128+f] + c2*bl[256+f];   // 2pi cancels
            float s = (col < 128) ? sinrev(p) : cosrev(p);
            float s3 = s*s*s, s5 = s3*s*s;
            tmp[0][j] = f2h(s); tmp[1][j] = f2h(s3); tmp[2][j] = f2h(s5);
        }
        #pragma unroll
        for (int pp = 0; pp < 3; ++pp)
            #pragma unroll
            for (int g = 0; g < 2; ++g) {
                uint4 v; memcpy(&v, &tmp[pp][g*8], 16);
                *(uint4*)&xa[((pp*32 + (colb>>3) + g)*32 + m)*8] = v;
            }
    }

    const int offs[9]    = {0,24576,32768,57344,65536,90112,98304,122880,131072};
    const int nchunks[9] = {24,8,24,8,24,8,24,8,24};

    for (int l = 0; l < 9; ++l) {
        int NC = nchunks[l];
        int mode = (l == 8) ? 2 : (l & 1);   // 0=sin-layer, 1=gemm+sin, 2=last
        const uint4* wp = (const uint4*)Wg + offs[l] + wv*128 + lane;
        f32x4 acc00 = {0.f,0.f,0.f,0.f}, acc01 = acc00, acc10 = acc00, acc11 = acc00;
        float bb0 = 0.f, bb1 = 0.f;
        if (mode == 1) {
            const float* br = b1s + ((l-1)>>1)*256;
            bb0 = br[wv*32 + lr]; bb1 = br[wv*32 + 16 + lr];
        }
        __syncthreads();                         // prior xa writes visible
        #pragma unroll 4
        for (int c = 0; c < NC; ++c) {
            uint4 u0 = wp[c*1024];               // cols wv*32+0..15
            uint4 u1 = wp[c*1024 + 64];          // cols wv*32+16..31
            half8 a0 = *(const half8*)&xa[((c*4 + lq)*32 + lr)*8];
            half8 a1 = *(const half8*)&xa[((c*4 + lq)*32 + 16 + lr)*8];
            half8 b0, b1v; memcpy(&b0, &u0, 16); memcpy(&b1v, &u1, 16);
            acc00 = __builtin_amdgcn_mfma_f32_16x16x32_f16(a0, b0,  acc00, 0,0,0);
            acc01 = __builtin_amdgcn_mfma_f32_16x16x32_f16(a0, b1v, acc01, 0,0,0);
            acc10 = __builtin_amdgcn_mfma_f32_16x16x32_f16(a1, b0,  acc10, 0,0,0);
            acc11 = __builtin_amdgcn_mfma_f32_16x16x32_f16(a1, b1v, acc11, 0,0,0);
        }
        __syncthreads();                         // all xa reads done
        // ---- epilogue ----
        #pragma unroll
        for (int rt = 0; rt < 2; ++rt)
            #pragma unroll
            for (int ct = 0; ct < 2; ++ct) {
                f32x4 A = rt==0 ? (ct==0?acc00:acc01) : (ct==0?acc10:acc11);
                int h = wv*32 + ct*16 + lr;
                float bb = ct==0 ? bb0 : bb1;
                #pragma unroll
                for (int r = 0; r < 4; ++r) {
                    float v = A[r];
                    int m = rt*16 + lq*4 + r;    // C row = quad*4 + reg (m89)
                    if (mode == 2) {
                        out[(size_t)(n0 + m)*256 + h] = v;
                    } else if (mode == 1) {
                        float s = sinrev(v + bb);   // weights pre-scaled 1/2pi
                        float s3 = s*s*s, s5 = s3*s*s;
                        xa[(((h>>3)     )*32 + m)*8 + (h&7)] = f2h(s);
                        xa[(((h>>3) + 32)*32 + m)*8 + (h&7)] = f2h(s3);
                        xa[(((h>>3) + 64)*32 + m)*8 + (h&7)] = f2h(s5);
                    } else {
                        xa[((h>>3)*32 + m)*8 + (h&7)] = f2h(v);
                    }
                }
            }
    }
}

// ---------------- launch ---------------------------------------------------
extern "C" void kernel_launch(void* const* d_in, const int* in_sizes, int n_in,
                              void* d_out, int out_size, void* d_ws, size_t ws_size,
                              hipStream_t stream)
{
    const float* coords = (const float*)d_in[0];
    const float* Bm     = (const float*)d_in[1];
    const float* w0     = (const float*)d_in[2];
    const float* ws     = (const float*)d_in[3];
    const float* wlast  = (const float*)d_in[4];
    const float* w1     = (const float*)d_in[5];
    const float* b1     = (const float*)d_in[6];
    float* out = (float*)d_out;

    unsigned short* Wg = (unsigned short*)d_ws;                    // 2.49 MB fp16
    float* b1s = (float*)((char*)d_ws + (size_t)WG_BLOCKS*16);     // 4 KB fp32

    dim3 pg(10, 8);
    prep_kernel<<<pg, 256, 0, stream>>>(w0, ws, wlast, w1, coords, b1, Wg, b1s, out);
    net_kernel<<<NROW/MT, 512, 0, stream>>>(coords, Bm, Wg, b1s, out);
}

// Round 7
// 128.463 us; speedup vs baseline: 3.8091x; 1.1660x over previous
//
#include <hip/hip_runtime.h>
#include <string.h>

#define NCRD 4096
#define NROW 8192
#define MT   32            // rows per block -> 256 blocks (1/CU)
#define WG_BLOCKS 155648   // total prepped weight size in 16B blocks

typedef __attribute__((ext_vector_type(8))) _Float16 half8;
typedef __attribute__((ext_vector_type(4))) float f32x4;

static __device__ __forceinline__ float sinrev(float t){ return __builtin_amdgcn_sinf(__builtin_amdgcn_fractf(t)); }
static __device__ __forceinline__ float cosrev(float t){ return __builtin_amdgcn_cosf(__builtin_amdgcn_fractf(t)); }
static __device__ __forceinline__ unsigned short f2h(float f){   // RNE f32->fp16
    _Float16 h = (_Float16)f;
    unsigned short u; memcpy(&u, &h, 2); return u;
}

// Weight uint4 index within a layer: idx = c*1024 + wv*128 + t*64 + lq*16 + lr
//   -> B[k = c*32 + lq*8 + j][col = wv*32 + t*16 + lr], j = 0..7 within the 16B.
// Sin layers (l even): terms {W, -W^3/6, W^5/120} stacked in k (K=768, 24 chunks).
// GEMM layers (l odd): W/(2pi) (K=256, 8 chunks).
__constant__ int c_offs[9] = {0,24576,32768,57344,65536,90112,98304,122880,131072};

// ---- prep: one coalesced uint4 store per thread; l==9: bias+coords --------
__global__ void prep_kernel(const float* __restrict__ w0, const float* __restrict__ ws,
                            const float* __restrict__ wlast, const float* __restrict__ w1,
                            const float* __restrict__ coords, const float* __restrict__ b1,
                            uint4* __restrict__ Wg, float* __restrict__ b1s,
                            float* __restrict__ out)
{
    int l = blockIdx.x, part = blockIdx.y, t = threadIdx.x;
    const float inv2pi = 0.15915494309189535f;
    if (l == 9) {
        int i = part*256 + t;                          // 0..24575
        if (i < 1024)   b1s[i] = b1[i]*inv2pi;
        if (i < NCRD*6) out[(size_t)NROW*256 + i] = coords[i];
        return;
    }
    bool sinl = !(l & 1);
    if (!sinl && part >= 32) return;                   // gemm layers: 8192 uint4
    const float* src;
    switch (l) {
        case 0: src = w0;          break;
        case 1: src = w1;          break;
        case 2: src = ws;          break;
        case 3: src = w1+65536;    break;
        case 4: src = ws+65536;    break;
        case 5: src = w1+2*65536;  break;
        case 6: src = ws+2*65536;  break;
        case 7: src = w1+3*65536;  break;
        default: src = wlast;      break;
    }
    int idx = part*256 + t;                 // uint4 index within layer
    int c  = idx >> 10, r = idx & 1023;
    int q  = r >> 7,  r2 = r & 127;
    int tt = r2 >> 6;
    int lq = (r2 >> 4) & 3, lr = r2 & 15;
    int col  = q*32 + tt*16 + lr;
    int keff = c*32 + lq*8;
    int term = keff >> 8, kk = keff & 255;
    const float* s = src + col*256 + kk;    // 8 consecutive floats
    unsigned short h[8];
    #pragma unroll
    for (int j = 0; j < 8; ++j) {
        float w = s[j], v;
        if (!sinl)          v = w * inv2pi;
        else if (term == 0) v = w;
        else if (term == 1) v = -w*w*w*(1.0f/6.0f);
        else { float w3 = w*w*w; v = w3*w*w*(1.0f/120.0f); }
        h[j] = f2h(v);
    }
    uint4 o; memcpy(&o, h, 16);
    Wg[c_offs[l] + idx] = o;                // coalesced 16B store
}

// ---------------- one layer, statically pipelined --------------------------
// MODE: 0 = sin-layer (identity fp16 write), 1 = gemm (sin+powers), 2 = last.
template<int MODE, int NC>
static __device__ __forceinline__ void do_layer(
    const uint4* __restrict__ wq,     // per-wave/lane weight base for this layer
    const float* __restrict__ br,     // bias row base (MODE 1)
    float* __restrict__ outg,         // global out (MODE 2)
    unsigned short* xa,
    int wv, int lq, int lr, int n0)
{
    f32x4 acc00 = {0.f,0.f,0.f,0.f}, acc01 = acc00, acc10 = acc00, acc11 = acc00;
    float bb0 = 0.f, bb1 = 0.f;
    if (MODE == 1) { bb0 = br[wv*32 + lr]; bb1 = br[wv*32 + 16 + lr]; }

    __syncthreads();                        // prior xa writes visible
    const half8* xa8 = (const half8*)xa;
    uint4 u0 = wq[0], u1 = wq[64];
    half8 a0 = xa8[(lq)*32 + lr];
    half8 a1 = xa8[(lq)*32 + 16 + lr];
    #pragma unroll
    for (int c = 0; c < NC; ++c) {
        uint4 nu0 = u0, nu1 = u1; half8 na0 = a0, na1 = a1;
        if (c + 1 < NC) {                   // static: folds at unroll
            nu0 = wq[(c+1)*1024];
            nu1 = wq[(c+1)*1024 + 64];
            na0 = xa8[((c+1)*4 + lq)*32 + lr];
            na1 = xa8[((c+1)*4 + lq)*32 + 16 + lr];
        }
        half8 b0, b1v; memcpy(&b0, &u0, 16); memcpy(&b1v, &u1, 16);
        acc00 = __builtin_amdgcn_mfma_f32_16x16x32_f16(a0, b0,  acc00, 0,0,0);
        acc01 = __builtin_amdgcn_mfma_f32_16x16x32_f16(a0, b1v, acc01, 0,0,0);
        acc10 = __builtin_amdgcn_mfma_f32_16x16x32_f16(a1, b0,  acc10, 0,0,0);
        acc11 = __builtin_amdgcn_mfma_f32_16x16x32_f16(a1, b1v, acc11, 0,0,0);
        u0 = nu0; u1 = nu1; a0 = na0; a1 = na1;
    }
    __syncthreads();                        // all xa reads done
    // ---- epilogue ----
    #pragma unroll
    for (int rt = 0; rt < 2; ++rt)
        #pragma unroll
        for (int ct = 0; ct < 2; ++ct) {
            f32x4 A = rt==0 ? (ct==0?acc00:acc01) : (ct==0?acc10:acc11);
            int h = wv*32 + ct*16 + lr;
            float bb = ct==0 ? bb0 : bb1;
            #pragma unroll
            for (int r = 0; r < 4; ++r) {
                float v = A[r];
                int m = rt*16 + lq*4 + r;   // C row = quad*4 + reg (m89)
                if (MODE == 2) {
                    outg[(size_t)(n0 + m)*256 + h] = v;
                } else if (MODE == 1) {
                    float s = sinrev(v + bb);   // weights pre-scaled 1/2pi
                    float s3 = s*s*s, s5 = s3*s*s;
                    xa[(((h>>3)     )*32 + m)*8 + (h&7)] = f2h(s);
                    xa[(((h>>3) + 32)*32 + m)*8 + (h&7)] = f2h(s3);
                    xa[(((h>>3) + 64)*32 + m)*8 + (h&7)] = f2h(s5);
                } else {
                    xa[((h>>3)*32 + m)*8 + (h&7)] = f2h(v);
                }
            }
        }
}

// ---------------- fused MFMA network kernel --------------------------------
__global__ __launch_bounds__(512)
void net_kernel(const float* __restrict__ coords, const float* __restrict__ Bm,
                const uint4* __restrict__ Wg, const float* __restrict__ b1s,
                float* __restrict__ out)
{
    __shared__ unsigned short xa[96*32*8];    // 48KB activations [kb][m][k%8]
    __shared__ float cb[MT*3];
    __shared__ float bl[384];

    int tid = threadIdx.x, lane = tid & 63, wv = tid >> 6;
    int lq = lane >> 4, lr = lane & 15;
    int n0 = blockIdx.x * MT;

    // ---- fourier features + powers -> xa ----
    for (int i = tid; i < MT*3; i += 512) {
        int r = i/3, d = i - 3*r, nv = n0 + r;
        cb[i] = (nv < NCRD) ? coords[nv*6 + d] : coords[(nv-NCRD)*6 + 3 + d];
    }
    for (int i = tid; i < 384; i += 512) bl[i] = Bm[i];
    __syncthreads();
    {
        int m = tid & 31, colb = (tid >> 5) * 16;       // 16 cols per thread
        float c0 = cb[m*3], c1 = cb[m*3+1], c2 = cb[m*3+2];
        unsigned short tmp[3][16];
        #pragma unroll
        for (int j = 0; j < 16; ++j) {
            int col = colb + j, f = col & 127;
            float p = c0*bl[f] + c1*bl[128+f] + c2*bl[256+f];   // 2pi cancels
            float s = (col < 128) ? sinrev(p) : cosrev(p);
            float s3 = s*s*s, s5 = s3*s*s;
            tmp[0][j] = f2h(s); tmp[1][j] = f2h(s3); tmp[2][j] = f2h(s5);
        }
        #pragma unroll
        for (int pp = 0; pp < 3; ++pp)
            #pragma unroll
            for (int g = 0; g < 2; ++g) {
                uint4 v; memcpy(&v, &tmp[pp][g*8], 16);
                *(uint4*)&xa[((pp*32 + (colb>>3) + g)*32 + m)*8] = v;
            }
    }
    // (each do_layer's entry barrier orders xa writes before reads)

    int wl = wv*128 + lane;
    do_layer<0,24>(Wg +      0 + wl, nullptr,   nullptr, xa, wv, lq, lr, n0);
    do_layer<1, 8>(Wg +  24576 + wl, b1s + 0,   nullptr, xa, wv, lq, lr, n0);
    do_layer<0,24>(Wg +  32768 + wl, nullptr,   nullptr, xa, wv, lq, lr, n0);
    do_layer<1, 8>(Wg +  57344 + wl, b1s + 256, nullptr, xa, wv, lq, lr, n0);
    do_layer<0,24>(Wg +  65536 + wl, nullptr,   nullptr, xa, wv, lq, lr, n0);
    do_layer<1, 8>(Wg +  90112 + wl, b1s + 512, nullptr, xa, wv, lq, lr, n0);
    do_layer<0,24>(Wg +  98304 + wl, nullptr,   nullptr, xa, wv, lq, lr, n0);
    do_layer<1, 8>(Wg + 122880 + wl, b1s + 768, nullptr, xa, wv, lq, lr, n0);
    do_layer<2,24>(Wg + 131072 + wl, nullptr,   out,     xa, wv, lq, lr, n0);
}

// ---------------- launch ---------------------------------------------------
extern "C" void kernel_launch(void* const* d_in, const int* in_sizes, int n_in,
                              void* d_out, int out_size, void* d_ws, size_t ws_size,
                              hipStream_t stream)
{
    const float* coords = (const float*)d_in[0];
    const float* Bm     = (const float*)d_in[1];
    const float* w0     = (const float*)d_in[2];
    const float* ws     = (const float*)d_in[3];
    const float* wlast  = (const float*)d_in[4];
    const float* w1     = (const float*)d_in[5];
    const float* b1     = (const float*)d_in[6];
    float* out = (float*)d_out;

    uint4* Wg  = (uint4*)d_ws;                                     // 2.49 MB fp16
    float* b1s = (float*)((char*)d_ws + (size_t)WG_BLOCKS*16);     // 4 KB fp32

    dim3 pg(10, 96);
    prep_kernel<<<pg, 256, 0, stream>>>(w0, ws, wlast, w1, coords, b1, Wg, b1s, out);
    net_kernel<<<NROW/MT, 512, 0, stream>>>(coords, Bm, Wg, b1s, out);
}

// Round 8
// 106.126 us; speedup vs baseline: 4.6108x; 1.2105x over previous
//
#include <hip/hip_runtime.h>
#include <string.h>

#define NCRD 4096
#define NROW 8192
#define MT   32            // rows per block -> 256 blocks (1/CU)
#define WG_U4 114688       // total prepped weight size in uint4 (1.75 MB fp16)

typedef __attribute__((ext_vector_type(8))) _Float16 half8;
typedef __attribute__((ext_vector_type(4))) float f32x4;

static __device__ __forceinline__ float sinrev(float t){ return __builtin_amdgcn_sinf(__builtin_amdgcn_fractf(t)); }
static __device__ __forceinline__ float cosrev(float t){ return __builtin_amdgcn_cosf(__builtin_amdgcn_fractf(t)); }
static __device__ __forceinline__ unsigned short f2h(float f){   // RNE f32->fp16
    _Float16 h = (_Float16)f;
    unsigned short u; memcpy(&u, &h, 2); return u;
}

// Weight uint4 index within a layer: idx = c*1024 + wv*128 + t*64 + lq*16 + lr
//   -> B[k = c*32 + lq*8 + j][col = wv*32 + t*16 + lr], j = 0..7 in the 16B.
// Sin layers (l even): terms {W, -W^3/6} stacked in k (K=512, 16 chunks).
// GEMM layers (l odd): W/(2pi) (K=256, 8 chunks). x^5 term dropped: |x.w|<~0.45
// so u^5/120 <= 2e-4 pointwise, ~1e-4 per output -- far below fp16 noise.
__constant__ int c_offs[9] = {0,16384,24576,40960,49152,65536,73728,90112,98304};

// ---- prep: one coalesced uint4 store per thread; l==9: bias+coords --------
__global__ void prep_kernel(const float* __restrict__ w0, const float* __restrict__ ws,
                            const float* __restrict__ wlast, const float* __restrict__ w1,
                            const float* __restrict__ coords, const float* __restrict__ b1,
                            uint4* __restrict__ Wg, float* __restrict__ b1s,
                            float* __restrict__ out)
{
    int l = blockIdx.x, part = blockIdx.y, t = threadIdx.x;
    const float inv2pi = 0.15915494309189535f;
    if (l == 9) {
        int base = part*256 + t;                       // 0..16383
        if (base < 1024) b1s[base] = b1[base]*inv2pi;
        for (int i = base; i < NCRD*6; i += 16384)
            out[(size_t)NROW*256 + i] = coords[i];
        return;
    }
    bool sinl = !(l & 1);
    if (!sinl && part >= 32) return;                   // gemm layers: 8192 uint4
    const float* src;
    switch (l) {
        case 0: src = w0;          break;
        case 1: src = w1;          break;
        case 2: src = ws;          break;
        case 3: src = w1+65536;    break;
        case 4: src = ws+65536;    break;
        case 5: src = w1+2*65536;  break;
        case 6: src = ws+2*65536;  break;
        case 7: src = w1+3*65536;  break;
        default: src = wlast;      break;
    }
    int idx = part*256 + t;                 // uint4 index within layer
    int c  = idx >> 10, r = idx & 1023;
    int q  = r >> 7,  r2 = r & 127;
    int tt = r2 >> 6;
    int lq = (r2 >> 4) & 3, lr = r2 & 15;
    int col  = q*32 + tt*16 + lr;
    int keff = c*32 + lq*8;
    int term = keff >> 8, kk = keff & 255;
    const float* s = src + col*256 + kk;    // 8 consecutive floats
    unsigned short h[8];
    #pragma unroll
    for (int j = 0; j < 8; ++j) {
        float w = s[j], v;
        if (!sinl)          v = w * inv2pi;
        else if (term == 0) v = w;
        else                v = -w*w*w*(1.0f/6.0f);
        h[j] = f2h(v);
    }
    uint4 o; memcpy(&o, h, 16);
    Wg[c_offs[l] + idx] = o;                // coalesced 16B store
}

// ---------------- one layer, deep-pipelined --------------------------------
// MODE: 0 = sin-layer (identity fp16 write), 1 = gemm (sin+x^3), 2 = last.
template<int MODE, int NC>
static __device__ __forceinline__ void do_layer(
    const uint4* __restrict__ wq,     // per-wave/lane weight base for this layer
    const float* __restrict__ br,     // bias row base (MODE 1)
    float* __restrict__ outg,         // global out (MODE 2)
    unsigned short* xa,
    int wv, int lq, int lr, int n0)
{
    constexpr int PD = 4;             // weight prefetch depth: 8 x 1KB coalesced in flight
    constexpr int PA = 2;             // A-fragment (LDS) prefetch depth
    f32x4 acc00 = {0.f,0.f,0.f,0.f}, acc01 = acc00, acc10 = acc00, acc11 = acc00;

    uint4 pu0[PD], pu1[PD];
    #pragma unroll
    for (int p = 0; p < PD; ++p) {    // issued BEFORE the barrier (independent of xa)
        pu0[p] = wq[p*1024];
        pu1[p] = wq[p*1024 + 64];
    }
    float bb0 = 0.f, bb1 = 0.f;
    if (MODE == 1) { bb0 = br[wv*32 + lr]; bb1 = br[wv*32 + 16 + lr]; }

    __syncthreads();                  // prior xa writes visible
    const half8* xa8 = (const half8*)xa;
    half8 pa0[PA], pa1[PA];
    #pragma unroll
    for (int p = 0; p < PA; ++p) {
        pa0[p] = xa8[(p*4 + lq)*32 + lr];
        pa1[p] = xa8[(p*4 + lq)*32 + 16 + lr];
    }
    #pragma unroll
    for (int c = 0; c < NC; ++c) {
        half8 b0, b1v;
        { uint4 t0 = pu0[c % PD], t1 = pu1[c % PD];
          memcpy(&b0, &t0, 16); memcpy(&b1v, &t1, 16); }
        half8 a0 = pa0[c % PA], a1 = pa1[c % PA];
        if (c + PD < NC) {            // static at unroll
            pu0[c % PD] = wq[(c+PD)*1024];
            pu1[c % PD] = wq[(c+PD)*1024 + 64];
        }
        if (c + PA < NC) {
            pa0[c % PA] = xa8[((c+PA)*4 + lq)*32 + lr];
            pa1[c % PA] = xa8[((c+PA)*4 + lq)*32 + 16 + lr];
        }
        acc00 = __builtin_amdgcn_mfma_f32_16x16x32_f16(a0, b0,  acc00, 0,0,0);
        acc01 = __builtin_amdgcn_mfma_f32_16x16x32_f16(a0, b1v, acc01, 0,0,0);
        acc10 = __builtin_amdgcn_mfma_f32_16x16x32_f16(a1, b0,  acc10, 0,0,0);
        acc11 = __builtin_amdgcn_mfma_f32_16x16x32_f16(a1, b1v, acc11, 0,0,0);
    }
    __syncthreads();                  // all xa reads done
    // ---- epilogue ----
    #pragma unroll
    for (int rt = 0; rt < 2; ++rt)
        #pragma unroll
        for (int ct = 0; ct < 2; ++ct) {
            f32x4 A = rt==0 ? (ct==0?acc00:acc01) : (ct==0?acc10:acc11);
            int h = wv*32 + ct*16 + lr;
            float bb = ct==0 ? bb0 : bb1;
            #pragma unroll
            for (int r = 0; r < 4; ++r) {
                float v = A[r];
                int m = rt*16 + lq*4 + r;   // C row = quad*4 + reg (m89)
                if (MODE == 2) {
                    outg[(size_t)(n0 + m)*256 + h] = v;
                } else if (MODE == 1) {
                    float s = sinrev(v + bb);   // weights pre-scaled 1/2pi
                    float s3 = s*s*s;
                    xa[(((h>>3)     )*32 + m)*8 + (h&7)] = f2h(s);
                    xa[(((h>>3) + 32)*32 + m)*8 + (h&7)] = f2h(s3);
                } else {
                    xa[((h>>3)*32 + m)*8 + (h&7)] = f2h(v);
                }
            }
        }
}

// ---------------- fused MFMA network kernel --------------------------------
__global__ __launch_bounds__(512)
void net_kernel(const float* __restrict__ coords, const float* __restrict__ Bm,
                const uint4* __restrict__ Wg, const float* __restrict__ b1s,
                float* __restrict__ out)
{
    __shared__ unsigned short xa[64*32*8];    // 32KB activations [kb][m][k%8]
    __shared__ float cb[MT*3];
    __shared__ float bl[384];

    int tid = threadIdx.x, lane = tid & 63, wv = tid >> 6;
    int lq = lane >> 4, lr = lane & 15;
    int n0 = blockIdx.x * MT;

    // ---- fourier features + x^3 powers -> xa ----
    for (int i = tid; i < MT*3; i += 512) {
        int r = i/3, d = i - 3*r, nv = n0 + r;
        cb[i] = (nv < NCRD) ? coords[nv*6 + d] : coords[(nv-NCRD)*6 + 3 + d];
    }
    for (int i = tid; i < 384; i += 512) bl[i] = Bm[i];
    __syncthreads();
    {
        int m = tid & 31, colb = (tid >> 5) * 16;       // 16 cols per thread
        float c0 = cb[m*3], c1 = cb[m*3+1], c2 = cb[m*3+2];
        unsigned short tmp[2][16];
        #pragma unroll
        for (int j = 0; j < 16; ++j) {
            int col = colb + j, f = col & 127;
            float p = c0*bl[f] + c1*bl[128+f] + c2*bl[256+f];   // 2pi cancels
            float s = (col < 128) ? sinrev(p) : cosrev(p);
            tmp[0][j] = f2h(s); tmp[1][j] = f2h(s*s*s);
        }
        #pragma unroll
        for (int pp = 0; pp < 2; ++pp)
            #pragma unroll
            for (int g = 0; g < 2; ++g) {
                uint4 v; memcpy(&v, &tmp[pp][g*8], 16);
                *(uint4*)&xa[((pp*32 + (colb>>3) + g)*32 + m)*8] = v;
            }
    }
    // (each do_layer's entry barrier orders xa writes before reads)

    int wl = wv*128 + lane;
    do_layer<0,16>(Wg +      0 + wl, nullptr,   nullptr, xa, wv, lq, lr, n0);
    do_layer<1, 8>(Wg +  16384 + wl, b1s + 0,   nullptr, xa, wv, lq, lr, n0);
    do_layer<0,16>(Wg +  24576 + wl, nullptr,   nullptr, xa, wv, lq, lr, n0);
    do_layer<1, 8>(Wg +  40960 + wl, b1s + 256, nullptr, xa, wv, lq, lr, n0);
    do_layer<0,16>(Wg +  49152 + wl, nullptr,   nullptr, xa, wv, lq, lr, n0);
    do_layer<1, 8>(Wg +  65536 + wl, b1s + 512, nullptr, xa, wv, lq, lr, n0);
    do_layer<0,16>(Wg +  73728 + wl, nullptr,   nullptr, xa, wv, lq, lr, n0);
    do_layer<1, 8>(Wg +  90112 + wl, b1s + 768, nullptr, xa, wv, lq, lr, n0);
    do_layer<2,16>(Wg +  98304 + wl, nullptr,   out,     xa, wv, lq, lr, n0);
}

// ---------------- launch ---------------------------------------------------
extern "C" void kernel_launch(void* const* d_in, const int* in_sizes, int n_in,
                              void* d_out, int out_size, void* d_ws, size_t ws_size,
                              hipStream_t stream)
{
    const float* coords = (const float*)d_in[0];
    const float* Bm     = (const float*)d_in[1];
    const float* w0     = (const float*)d_in[2];
    const float* ws     = (const float*)d_in[3];
    const float* wlast  = (const float*)d_in[4];
    const float* w1     = (const float*)d_in[5];
    const float* b1     = (const float*)d_in[6];
    float* out = (float*)d_out;

    uint4* Wg  = (uint4*)d_ws;                                   // 1.75 MB fp16
    float* b1s = (float*)((char*)d_ws + (size_t)WG_U4*16);       // 4 KB fp32

    dim3 pg(10, 64);
    prep_kernel<<<pg, 256, 0, stream>>>(w0, ws, wlast, w1, coords, b1, Wg, b1s, out);
    net_kernel<<<NROW/MT, 512, 0, stream>>>(coords, Bm, Wg, b1s, out);
}

// Round 9
// 102.677 us; speedup vs baseline: 4.7657x; 1.0336x over previous
//
#include <hip/hip_runtime.h>
#include <string.h>

#define NCRD 4096
#define NROW 8192
#define MT   32            // rows per block -> 256 blocks (1/CU)
#define WG_U4 114688       // total prepped weight size in uint4 (1.75 MB fp16)

typedef __attribute__((ext_vector_type(8))) _Float16 half8;
typedef __attribute__((ext_vector_type(4))) float f32x4;

static __device__ __forceinline__ float sinrev(float t){ return __builtin_amdgcn_sinf(__builtin_amdgcn_fractf(t)); }
static __device__ __forceinline__ float cosrev(float t){ return __builtin_amdgcn_cosf(__builtin_amdgcn_fractf(t)); }
static __device__ __forceinline__ unsigned short f2h(float f){   // RNE f32->fp16
    _Float16 h = (_Float16)f;
    unsigned short u; memcpy(&u, &h, 2); return u;
}

// Weight uint4 index within a layer: idx = c*1024 + wv*128 + t*64 + lq*16 + lr
//   -> B[k = c*32 + lq*8 + j][col = wv*32 + t*16 + lr], j = 0..7 in the 16B.
// Sin layers (l even): terms {W, -W^3/6} stacked in k (K=512, 16 chunks).
// GEMM layers (l odd): W/(2pi) (K=256, 8 chunks). x^5 term dropped: |x.w|<~0.45
// so u^5/120 <= 2e-4 pointwise -- far below fp16 noise.
__constant__ int c_offs[9] = {0,16384,24576,40960,49152,65536,73728,90112,98304};

// ---- prep: one coalesced uint4 store per thread; l==9: bias+coords --------
__global__ void prep_kernel(const float* __restrict__ w0, const float* __restrict__ ws,
                            const float* __restrict__ wlast, const float* __restrict__ w1,
                            const float* __restrict__ coords, const float* __restrict__ b1,
                            uint4* __restrict__ Wg, float* __restrict__ b1s,
                            float* __restrict__ out)
{
    int l = blockIdx.x, part = blockIdx.y, t = threadIdx.x;
    const float inv2pi = 0.15915494309189535f;
    if (l == 9) {
        int base = part*256 + t;                       // 0..16383
        if (base < 1024) b1s[base] = b1[base]*inv2pi;
        for (int i = base; i < NCRD*6; i += 16384)
            out[(size_t)NROW*256 + i] = coords[i];
        return;
    }
    bool sinl = !(l & 1);
    if (!sinl && part >= 32) return;                   // gemm layers: 8192 uint4
    const float* src;
    switch (l) {
        case 0: src = w0;          break;
        case 1: src = w1;          break;
        case 2: src = ws;          break;
        case 3: src = w1+65536;    break;
        case 4: src = ws+65536;    break;
        case 5: src = w1+2*65536;  break;
        case 6: src = ws+2*65536;  break;
        case 7: src = w1+3*65536;  break;
        default: src = wlast;      break;
    }
    int idx = part*256 + t;                 // uint4 index within layer
    int c  = idx >> 10, r = idx & 1023;
    int q  = r >> 7,  r2 = r & 127;
    int tt = r2 >> 6;
    int lq = (r2 >> 4) & 3, lr = r2 & 15;
    int col  = q*32 + tt*16 + lr;
    int keff = c*32 + lq*8;
    int term = keff >> 8, kk = keff & 255;
    const float* s = src + col*256 + kk;    // 8 consecutive floats
    unsigned short h[8];
    #pragma unroll
    for (int j = 0; j < 8; ++j) {
        float w = s[j], v;
        if (!sinl)          v = w * inv2pi;
        else if (term == 0) v = w;
        else                v = -w*w*w*(1.0f/6.0f);
        h[j] = f2h(v);
    }
    uint4 o; memcpy(&o, h, 16);
    Wg[c_offs[l] + idx] = o;                // coalesced 16B store
}

// ---------------- one layer, deep-pipelined --------------------------------
// MODE: 0 = sin-layer (identity fp16 write), 1 = gemm (sin+x^3), 2 = last.
template<int MODE, int NC>
static __device__ __forceinline__ void do_layer(
    const uint4* __restrict__ wq,     // per-wave/lane weight base for this layer
    const float* __restrict__ br,     // bias row base (MODE 1)
    float* __restrict__ outg,         // global out (MODE 2)
    unsigned short* xa,
    int wv, int lq, int lr, int n0)
{
    constexpr int PD = 8;             // weight prefetch depth: 16 x 1KB in flight/wave
    constexpr int PA = 2;             // A-fragment (LDS) prefetch depth
    f32x4 acc00 = {0.f,0.f,0.f,0.f}, acc01 = acc00, acc10 = acc00, acc11 = acc00;

    uint4 pu0[PD], pu1[PD];
    #pragma unroll
    for (int p = 0; p < PD; ++p) {    // issued BEFORE the barrier (independent of xa)
        if (p < NC) { pu0[p] = wq[p*1024]; pu1[p] = wq[p*1024 + 64]; }
    }
    float bb0 = 0.f, bb1 = 0.f;
    if (MODE == 1) { bb0 = br[wv*32 + lr]; bb1 = br[wv*32 + 16 + lr]; }

    __syncthreads();                  // prior xa writes visible
    const half8* xa8 = (const half8*)xa;
    half8 pa0[PA], pa1[PA];
    #pragma unroll
    for (int p = 0; p < PA; ++p) {
        pa0[p] = xa8[(p*4 + lq)*32 + lr];
        pa1[p] = xa8[(p*4 + lq)*32 + 16 + lr];
    }
    #pragma unroll
    for (int c = 0; c < NC; ++c) {
        half8 b0, b1v;
        { uint4 t0 = pu0[c % PD], t1 = pu1[c % PD];
          memcpy(&b0, &t0, 16); memcpy(&b1v, &t1, 16); }
        half8 a0 = pa0[c % PA], a1 = pa1[c % PA];
        if (c + PD < NC) {            // static at unroll
            pu0[c % PD] = wq[(c+PD)*1024];
            pu1[c % PD] = wq[(c+PD)*1024 + 64];
        }
        if (c + PA < NC) {
            pa0[c % PA] = xa8[((c+PA)*4 + lq)*32 + lr];
            pa1[c % PA] = xa8[((c+PA)*4 + lq)*32 + 16 + lr];
        }
        acc00 = __builtin_amdgcn_mfma_f32_16x16x32_f16(a0, b0,  acc00, 0,0,0);
        acc01 = __builtin_amdgcn_mfma_f32_16x16x32_f16(a0, b1v, acc01, 0,0,0);
        acc10 = __builtin_amdgcn_mfma_f32_16x16x32_f16(a1, b0,  acc10, 0,0,0);
        acc11 = __builtin_amdgcn_mfma_f32_16x16x32_f16(a1, b1v, acc11, 0,0,0);
    }
    __syncthreads();                  // all xa reads done
    // ---- epilogue ----
    #pragma unroll
    for (int rt = 0; rt < 2; ++rt)
        #pragma unroll
        for (int ct = 0; ct < 2; ++ct) {
            f32x4 A = rt==0 ? (ct==0?acc00:acc01) : (ct==0?acc10:acc11);
            int h = wv*32 + ct*16 + lr;
            float bb = ct==0 ? bb0 : bb1;
            #pragma unroll
            for (int r = 0; r < 4; ++r) {
                float v = A[r];
                int m = rt*16 + lq*4 + r;   // C row = quad*4 + reg (m89)
                if (MODE == 2) {
                    outg[(size_t)(n0 + m)*256 + h] = v;
                } else if (MODE == 1) {
                    float s = sinrev(v + bb);   // weights pre-scaled 1/2pi
                    float s3 = s*s*s;
                    xa[(((h>>3)     )*32 + m)*8 + (h&7)] = f2h(s);
                    xa[(((h>>3) + 32)*32 + m)*8 + (h&7)] = f2h(s3);
                } else {
                    xa[((h>>3)*32 + m)*8 + (h&7)] = f2h(v);
                }
            }
        }
}

// ---------------- fused MFMA network kernel --------------------------------
// __launch_bounds__(512, 2): 2 waves/EU -> 1 block/CU co-residency target,
// giving the allocator the full ~256-VGPR budget for the deep prefetch.
__global__ __launch_bounds__(512, 2)
void net_kernel(const float* __restrict__ coords, const float* __restrict__ Bm,
                const uint4* __restrict__ Wg, const float* __restrict__ b1s,
                float* __restrict__ out)
{
    __shared__ unsigned short xa[64*32*8];    // 32KB activations [kb][m][k%8]
    __shared__ float cb[MT*3];
    __shared__ float bl[384];

    int tid = threadIdx.x, lane = tid & 63, wv = tid >> 6;
    int lq = lane >> 4, lr = lane & 15;
    int n0 = blockIdx.x * MT;

    // ---- fourier features + x^3 powers -> xa ----
    for (int i = tid; i < MT*3; i += 512) {
        int r = i/3, d = i - 3*r, nv = n0 + r;
        cb[i] = (nv < NCRD) ? coords[nv*6 + d] : coords[(nv-NCRD)*6 + 3 + d];
    }
    for (int i = tid; i < 384; i += 512) bl[i] = Bm[i];
    __syncthreads();
    {
        int m = tid & 31, colb = (tid >> 5) * 16;       // 16 cols per thread
        float c0 = cb[m*3], c1 = cb[m*3+1], c2 = cb[m*3+2];
        unsigned short tmp[2][16];
        #pragma unroll
        for (int j = 0; j < 16; ++j) {
            int col = colb + j, f = col & 127;
            float p = c0*bl[f] + c1*bl[128+f] + c2*bl[256+f];   // 2pi cancels
            float s = (col < 128) ? sinrev(p) : cosrev(p);
            tmp[0][j] = f2h(s); tmp[1][j] = f2h(s*s*s);
        }
        #pragma unroll
        for (int pp = 0; pp < 2; ++pp)
            #pragma unroll
            for (int g = 0; g < 2; ++g) {
                uint4 v; memcpy(&v, &tmp[pp][g*8], 16);
                *(uint4*)&xa[((pp*32 + (colb>>3) + g)*32 + m)*8] = v;
            }
    }
    // (each do_layer's entry barrier orders xa writes before reads)

    int wl = wv*128 + lane;
    do_layer<0,16>(Wg +      0 + wl, nullptr,   nullptr, xa, wv, lq, lr, n0);
    do_layer<1, 8>(Wg +  16384 + wl, b1s + 0,   nullptr, xa, wv, lq, lr, n0);
    do_layer<0,16>(Wg +  24576 + wl, nullptr,   nullptr, xa, wv, lq, lr, n0);
    do_layer<1, 8>(Wg +  40960 + wl, b1s + 256, nullptr, xa, wv, lq, lr, n0);
    do_layer<0,16>(Wg +  49152 + wl, nullptr,   nullptr, xa, wv, lq, lr, n0);
    do_layer<1, 8>(Wg +  65536 + wl, b1s + 512, nullptr, xa, wv, lq, lr, n0);
    do_layer<0,16>(Wg +  73728 + wl, nullptr,   nullptr, xa, wv, lq, lr, n0);
    do_layer<1, 8>(Wg +  90112 + wl, b1s + 768, nullptr, xa, wv, lq, lr, n0);
    do_layer<2,16>(Wg +  98304 + wl, nullptr,   out,     xa, wv, lq, lr, n0);
}

// ---------------- launch ---------------------------------------------------
extern "C" void kernel_launch(void* const* d_in, const int* in_sizes, int n_in,
                              void* d_out, int out_size, void* d_ws, size_t ws_size,
                              hipStream_t stream)
{
    const float* coords = (const float*)d_in[0];
    const float* Bm     = (const float*)d_in[1];
    const float* w0     = (const float*)d_in[2];
    const float* ws     = (const float*)d_in[3];
    const float* wlast  = (const float*)d_in[4];
    const float* w1     = (const float*)d_in[5];
    const float* b1     = (const float*)d_in[6];
    float* out = (float*)d_out;

    uint4* Wg  = (uint4*)d_ws;                                   // 1.75 MB fp16
    float* b1s = (float*)((char*)d_ws + (size_t)WG_U4*16);       // 4 KB fp32

    dim3 pg(10, 64);
    prep_kernel<<<pg, 256, 0, stream>>>(w0, ws, wlast, w1, coords, b1, Wg, b1s, out);
    net_kernel<<<NROW/MT, 512, 0, stream>>>(coords, Bm, Wg, b1s, out);
}

// Round 10
// 97.735 us; speedup vs baseline: 5.0067x; 1.0506x over previous
//
#include <hip/hip_runtime.h>
#include <string.h>

#define NCRD 4096
#define NROW 8192
#define MT   32            // rows per block -> 256 blocks (1/CU)
#define WG_U4 114688       // total prepped weight size in uint4 (1.75 MB fp16)

typedef __attribute__((ext_vector_type(8))) _Float16 half8;
typedef __attribute__((ext_vector_type(4))) float f32x4;
typedef __attribute__((ext_vector_type(4))) int   i32x4;

static __device__ __forceinline__ float sinrev(float t){ return __builtin_amdgcn_sinf(__builtin_amdgcn_fractf(t)); }
static __device__ __forceinline__ float cosrev(float t){ return __builtin_amdgcn_cosf(__builtin_amdgcn_fractf(t)); }
static __device__ __forceinline__ unsigned short f2h(float f){   // RNE f32->fp16
    _Float16 h = (_Float16)f;
    unsigned short u; memcpy(&u, &h, 2); return u;
}

// Scheduler-opaque 16B global load: cannot be sunk/reordered by the compiler.
static __device__ __forceinline__ i32x4 gload16(const uint4* p){
    i32x4 r;
    asm volatile("global_load_dwordx4 %0, %1, off" : "=v"(r) : "v"(p) : "memory");
    return r;
}
// Explicit vmcnt gate, data-tied to the two regs about to be consumed so the
// MFMAs cannot be hoisted above it. K folds to a constant under full unroll.
static __device__ __forceinline__ void vmwaitK(int K, i32x4& a, i32x4& b){
    if (K >= 16)      asm volatile("s_waitcnt vmcnt(16)" : "+v"(a), "+v"(b));
    else if (K >= 14) asm volatile("s_waitcnt vmcnt(14)" : "+v"(a), "+v"(b));
    else if (K >= 12) asm volatile("s_waitcnt vmcnt(12)" : "+v"(a), "+v"(b));
    else if (K >= 10) asm volatile("s_waitcnt vmcnt(10)" : "+v"(a), "+v"(b));
    else if (K >= 8)  asm volatile("s_waitcnt vmcnt(8)"  : "+v"(a), "+v"(b));
    else if (K >= 6)  asm volatile("s_waitcnt vmcnt(6)"  : "+v"(a), "+v"(b));
    else if (K >= 4)  asm volatile("s_waitcnt vmcnt(4)"  : "+v"(a), "+v"(b));
    else if (K >= 2)  asm volatile("s_waitcnt vmcnt(2)"  : "+v"(a), "+v"(b));
    else              asm volatile("s_waitcnt vmcnt(0)"  : "+v"(a), "+v"(b));
}

// Weight uint4 index within a layer: idx = c*1024 + wv*128 + t*64 + lq*16 + lr
//   -> B[k = c*32 + lq*8 + j][col = wv*32 + t*16 + lr], j = 0..7 in the 16B.
// Sin layers (l even): terms {W, -W^3/6} stacked in k (K=512, 16 chunks).
// GEMM layers (l odd): W/(2pi) (K=256, 8 chunks).
__constant__ int c_offs[9] = {0,16384,24576,40960,49152,65536,73728,90112,98304};

// ---- prep: one coalesced uint4 store per thread; l==9: bias+coords --------
__global__ void prep_kernel(const float* __restrict__ w0, const float* __restrict__ ws,
                            const float* __restrict__ wlast, const float* __restrict__ w1,
                            const float* __restrict__ coords, const float* __restrict__ b1,
                            uint4* __restrict__ Wg, float* __restrict__ b1s,
                            float* __restrict__ out)
{
    int l = blockIdx.x, part = blockIdx.y, t = threadIdx.x;
    const float inv2pi = 0.15915494309189535f;
    if (l == 9) {
        int base = part*256 + t;                       // 0..16383
        if (base < 1024) b1s[base] = b1[base]*inv2pi;
        for (int i = base; i < NCRD*6; i += 16384)
            out[(size_t)NROW*256 + i] = coords[i];
        return;
    }
    bool sinl = !(l & 1);
    if (!sinl && part >= 32) return;                   // gemm layers: 8192 uint4
    const float* src;
    switch (l) {
        case 0: src = w0;          break;
        case 1: src = w1;          break;
        case 2: src = ws;          break;
        case 3: src = w1+65536;    break;
        case 4: src = ws+65536;    break;
        case 5: src = w1+2*65536;  break;
        case 6: src = ws+2*65536;  break;
        case 7: src = w1+3*65536;  break;
        default: src = wlast;      break;
    }
    int idx = part*256 + t;                 // uint4 index within layer
    int c  = idx >> 10, r = idx & 1023;
    int q  = r >> 7,  r2 = r & 127;
    int tt = r2 >> 6;
    int lq = (r2 >> 4) & 3, lr = r2 & 15;
    int col  = q*32 + tt*16 + lr;
    int keff = c*32 + lq*8;
    int term = keff >> 8, kk = keff & 255;
    const float* s = src + col*256 + kk;    // 8 consecutive floats
    unsigned short h[8];
    #pragma unroll
    for (int j = 0; j < 8; ++j) {
        float w = s[j], v;
        if (!sinl)          v = w * inv2pi;
        else if (term == 0) v = w;
        else                v = -w*w*w*(1.0f/6.0f);
        h[j] = f2h(v);
    }
    uint4 o; memcpy(&o, h, 16);
    Wg[c_offs[l] + idx] = o;                // coalesced 16B store
}

// ---------------- one layer, asm-pinned pipeline ---------------------------
// MODE: 0 = sin-layer (identity fp16 write), 1 = gemm (sin+x^3), 2 = last.
template<int MODE, int NC>
static __device__ __forceinline__ void do_layer(
    const uint4* __restrict__ wq,     // per-wave/lane weight base for this layer
    const float* __restrict__ br,     // bias row base (MODE 1)
    float* __restrict__ outg,         // global out (MODE 2)
    unsigned short* xa,
    int wv, int lq, int lr, int n0)
{
    constexpr int PD = 8;             // chunks in flight (16 x 1KB loads/wave)
    constexpr int RS = PD + 1;        // ring slots: consume slot != issue slot (no WAR)
    constexpr int PA = 2;             // A-fragment (LDS) prefetch depth
    f32x4 acc00 = {0.f,0.f,0.f,0.f}, acc01 = acc00, acc10 = acc00, acc11 = acc00;

    i32x4 ring0[RS], ring1[RS];
    #pragma unroll
    for (int p = 0; p < PD; ++p)      // prologue: issued before the barrier
        if (p < NC) {
            ring0[p % RS] = gload16(wq + p*1024);
            ring1[p % RS] = gload16(wq + p*1024 + 64);
        }

    __syncthreads();                  // prior xa writes visible
    const half8* xa8 = (const half8*)xa;
    half8 pa0[PA], pa1[PA];
    #pragma unroll
    for (int p = 0; p < PA; ++p) {
        pa0[p] = xa8[(p*4 + lq)*32 + lr];
        pa1[p] = xa8[(p*4 + lq)*32 + 16 + lr];
    }
    #pragma unroll
    for (int c = 0; c < NC; ++c) {
        if (c + PD < NC) {            // issue into slot consumed PD iters ago
            ring0[(c+PD) % RS] = gload16(wq + (c+PD)*1024);
            ring1[(c+PD) % RS] = gload16(wq + (c+PD)*1024 + 64);
        }
        int K = 2*(NC-1-c);           // folds to a constant under unroll
        vmwaitK(K > 16 ? 16 : K, ring0[c % RS], ring1[c % RS]);
        half8 b0, b1v, a0 = pa0[c % PA], a1 = pa1[c % PA];
        { i32x4 t0 = ring0[c % RS], t1 = ring1[c % RS];
          memcpy(&b0, &t0, 16); memcpy(&b1v, &t1, 16); }
        if (c + PA < NC) {
            pa0[c % PA] = xa8[((c+PA)*4 + lq)*32 + lr];
            pa1[c % PA] = xa8[((c+PA)*4 + lq)*32 + 16 + lr];
        }
        acc00 = __builtin_amdgcn_mfma_f32_16x16x32_f16(a0, b0,  acc00, 0,0,0);
        acc01 = __builtin_amdgcn_mfma_f32_16x16x32_f16(a0, b1v, acc01, 0,0,0);
        acc10 = __builtin_amdgcn_mfma_f32_16x16x32_f16(a1, b0,  acc10, 0,0,0);
        acc11 = __builtin_amdgcn_mfma_f32_16x16x32_f16(a1, b1v, acc11, 0,0,0);
    }
    __syncthreads();                  // all xa reads done
    // ---- epilogue (bias loaded here: keeps K-loop vmcnt exclusively ours) --
    float bb0 = 0.f, bb1 = 0.f;
    if (MODE == 1) { bb0 = br[wv*32 + lr]; bb1 = br[wv*32 + 16 + lr]; }
    #pragma unroll
    for (int rt = 0; rt < 2; ++rt)
        #pragma unroll
        for (int ct = 0; ct < 2; ++ct) {
            f32x4 A = rt==0 ? (ct==0?acc00:acc01) : (ct==0?acc10:acc11);
            int h = wv*32 + ct*16 + lr;
            float bb = ct==0 ? bb0 : bb1;
            #pragma unroll
            for (int r = 0; r < 4; ++r) {
                float v = A[r];
                int m = rt*16 + lq*4 + r;   // C row = quad*4 + reg (m89)
                if (MODE == 2) {
                    outg[(size_t)(n0 + m)*256 + h] = v;
                } else if (MODE == 1) {
                    float s = sinrev(v + bb);   // weights pre-scaled 1/2pi
                    float s3 = s*s*s;
                    xa[(((h>>3)     )*32 + m)*8 + (h&7)] = f2h(s);
                    xa[(((h>>3) + 32)*32 + m)*8 + (h&7)] = f2h(s3);
                } else {
                    xa[((h>>3)*32 + m)*8 + (h&7)] = f2h(v);
                }
            }
        }
}

// ---------------- fused MFMA network kernel --------------------------------
__global__ __launch_bounds__(512, 2)
void net_kernel(const float* __restrict__ coords, const float* __restrict__ Bm,
                const uint4* __restrict__ Wg, const float* __restrict__ b1s,
                float* __restrict__ out)
{
    __shared__ unsigned short xa[64*32*8];    // 32KB activations [kb][m][k%8]
    __shared__ float cb[MT*3];
    __shared__ float bl[384];

    int tid = threadIdx.x, lane = tid & 63, wv = tid >> 6;
    int lq = lane >> 4, lr = lane & 15;
    int n0 = blockIdx.x * MT;

    // ---- fourier features + x^3 powers -> xa ----
    for (int i = tid; i < MT*3; i += 512) {
        int r = i/3, d = i - 3*r, nv = n0 + r;
        cb[i] = (nv < NCRD) ? coords[nv*6 + d] : coords[(nv-NCRD)*6 + 3 + d];
    }
    for (int i = tid; i < 384; i += 512) bl[i] = Bm[i];
    __syncthreads();
    {
        int m = tid & 31, colb = (tid >> 5) * 16;       // 16 cols per thread
        float c0 = cb[m*3], c1 = cb[m*3+1], c2 = cb[m*3+2];
        unsigned short tmp[2][16];
        #pragma unroll
        for (int j = 0; j < 16; ++j) {
            int col = colb + j, f = col & 127;
            float p = c0*bl[f] + c1*bl[128+f] + c2*bl[256+f];   // 2pi cancels
            float s = (col < 128) ? sinrev(p) : cosrev(p);
            tmp[0][j] = f2h(s); tmp[1][j] = f2h(s*s*s);
        }
        #pragma unroll
        for (int pp = 0; pp < 2; ++pp)
            #pragma unroll
            for (int g = 0; g < 2; ++g) {
                uint4 v; memcpy(&v, &tmp[pp][g*8], 16);
                *(uint4*)&xa[((pp*32 + (colb>>3) + g)*32 + m)*8] = v;
            }
    }
    // (each do_layer's entry barrier orders xa writes before reads)

    int wl = wv*128 + lane;
    do_layer<0,16>(Wg +      0 + wl, nullptr,   nullptr, xa, wv, lq, lr, n0);
    do_layer<1, 8>(Wg +  16384 + wl, b1s + 0,   nullptr, xa, wv, lq, lr, n0);
    do_layer<0,16>(Wg +  24576 + wl, nullptr,   nullptr, xa, wv, lq, lr, n0);
    do_layer<1, 8>(Wg +  40960 + wl, b1s + 256, nullptr, xa, wv, lq, lr, n0);
    do_layer<0,16>(Wg +  49152 + wl, nullptr,   nullptr, xa, wv, lq, lr, n0);
    do_layer<1, 8>(Wg +  65536 + wl, b1s + 512, nullptr, xa, wv, lq, lr, n0);
    do_layer<0,16>(Wg +  73728 + wl, nullptr,   nullptr, xa, wv, lq, lr, n0);
    do_layer<1, 8>(Wg +  90112 + wl, b1s + 768, nullptr, xa, wv, lq, lr, n0);
    do_layer<2,16>(Wg +  98304 + wl, nullptr,   out,     xa, wv, lq, lr, n0);
}

// ---------------- launch ---------------------------------------------------
extern "C" void kernel_launch(void* const* d_in, const int* in_sizes, int n_in,
                              void* d_out, int out_size, void* d_ws, size_t ws_size,
                              hipStream_t stream)
{
    const float* coords = (const float*)d_in[0];
    const float* Bm     = (const float*)d_in[1];
    const float* w0     = (const float*)d_in[2];
    const float* ws     = (const float*)d_in[3];
    const float* wlast  = (const float*)d_in[4];
    const float* w1     = (const float*)d_in[5];
    const float* b1     = (const float*)d_in[6];
    float* out = (float*)d_out;

    uint4* Wg  = (uint4*)d_ws;                                   // 1.75 MB fp16
    float* b1s = (float*)((char*)d_ws + (size_t)WG_U4*16);       // 4 KB fp32

    dim3 pg(10, 64);
    prep_kernel<<<pg, 256, 0, stream>>>(w0, ws, wlast, w1, coords, b1, Wg, b1s, out);
    net_kernel<<<NROW/MT, 512, 0, stream>>>(coords, Bm, Wg, b1s, out);
}

// Round 11
// 96.634 us; speedup vs baseline: 5.0637x; 1.0114x over previous
//
#include <hip/hip_runtime.h>
#include <string.h>

#define NCRD 4096
#define NROW 8192
#define MT   32            // rows per block -> 256 blocks (1/CU)
#define WG_U4 114688       // total prepped weight size in uint4 (1.75 MB fp16)

typedef __attribute__((ext_vector_type(8))) _Float16 half8;
typedef __attribute__((ext_vector_type(4))) float f32x4;
typedef __attribute__((ext_vector_type(4))) int   i32x4;

static __device__ __forceinline__ float sinrev(float t){ return __builtin_amdgcn_sinf(__builtin_amdgcn_fractf(t)); }
static __device__ __forceinline__ float cosrev(float t){ return __builtin_amdgcn_cosf(__builtin_amdgcn_fractf(t)); }
static __device__ __forceinline__ unsigned short f2h(float f){   // RNE f32->fp16
    _Float16 h = (_Float16)f;
    unsigned short u; memcpy(&u, &h, 2); return u;
}

// Scheduler-opaque 16B global load: cannot be sunk/reordered by the compiler.
static __device__ __forceinline__ i32x4 gload16(const uint4* p){
    i32x4 r;
    asm volatile("global_load_dwordx4 %0, %1, off" : "=v"(r) : "v"(p) : "memory");
    return r;
}
// Explicit vmcnt gate, data-tied to the reg about to be consumed.
// K folds to a constant under full unroll.
static __device__ __forceinline__ void vmwaitK(int K, i32x4& a){
    if (K >= 8)      asm volatile("s_waitcnt vmcnt(8)" : "+v"(a));
    else if (K == 7) asm volatile("s_waitcnt vmcnt(7)" : "+v"(a));
    else if (K == 6) asm volatile("s_waitcnt vmcnt(6)" : "+v"(a));
    else if (K == 5) asm volatile("s_waitcnt vmcnt(5)" : "+v"(a));
    else if (K == 4) asm volatile("s_waitcnt vmcnt(4)" : "+v"(a));
    else if (K == 3) asm volatile("s_waitcnt vmcnt(3)" : "+v"(a));
    else if (K == 2) asm volatile("s_waitcnt vmcnt(2)" : "+v"(a));
    else if (K == 1) asm volatile("s_waitcnt vmcnt(1)" : "+v"(a));
    else             asm volatile("s_waitcnt vmcnt(0)" : "+v"(a));
}

// Weight uint4 index within a layer: idx = c*1024 + w*64 + lq*16 + lr
//   -> B[k = c*32 + lq*8 + j][col = w*16 + lr], j = 0..7 in the 16B.
// (identical to prior rounds' layout: w = 2q+t)
// Sin layers (l even): terms {W, -W^3/6} stacked in k (K=512, 16 chunks).
// GEMM layers (l odd): W/(2pi) (K=256, 8 chunks).
__constant__ int c_offs[9] = {0,16384,24576,40960,49152,65536,73728,90112,98304};

// ---- prep: one coalesced uint4 store per thread; l==9: bias+coords --------
__global__ void prep_kernel(const float* __restrict__ w0, const float* __restrict__ ws,
                            const float* __restrict__ wlast, const float* __restrict__ w1,
                            const float* __restrict__ coords, const float* __restrict__ b1,
                            uint4* __restrict__ Wg, float* __restrict__ b1s,
                            float* __restrict__ out)
{
    int l = blockIdx.x, part = blockIdx.y, t = threadIdx.x;
    const float inv2pi = 0.15915494309189535f;
    if (l == 9) {
        int base = part*256 + t;                       // 0..16383
        if (base < 1024) b1s[base] = b1[base]*inv2pi;
        for (int i = base; i < NCRD*6; i += 16384)
            out[(size_t)NROW*256 + i] = coords[i];
        return;
    }
    bool sinl = !(l & 1);
    if (!sinl && part >= 32) return;                   // gemm layers: 8192 uint4
    const float* src;
    switch (l) {
        case 0: src = w0;          break;
        case 1: src = w1;          break;
        case 2: src = ws;          break;
        case 3: src = w1+65536;    break;
        case 4: src = ws+65536;    break;
        case 5: src = w1+2*65536;  break;
        case 6: src = ws+2*65536;  break;
        case 7: src = w1+3*65536;  break;
        default: src = wlast;      break;
    }
    int idx = part*256 + t;                 // uint4 index within layer
    int c  = idx >> 10, r = idx & 1023;
    int q  = r >> 7,  r2 = r & 127;
    int tt = r2 >> 6;
    int lq = (r2 >> 4) & 3, lr = r2 & 15;
    int col  = q*32 + tt*16 + lr;
    int keff = c*32 + lq*8;
    int term = keff >> 8, kk = keff & 255;
    const float* s = src + col*256 + kk;    // 8 consecutive floats
    unsigned short h[8];
    #pragma unroll
    for (int j = 0; j < 8; ++j) {
        float w = s[j], v;
        if (!sinl)          v = w * inv2pi;
        else if (term == 0) v = w;
        else                v = -w*w*w*(1.0f/6.0f);
        h[j] = f2h(v);
    }
    uint4 o; memcpy(&o, h, 16);
    Wg[c_offs[l] + idx] = o;                // coalesced 16B store
}

// ---------------- one layer: 16 waves, 1 load/chunk/wave -------------------
// MODE: 0 = sin-layer (identity fp16 write), 1 = gemm (sin+x^3), 2 = last.
// Wave wv owns cols wv*16..wv*16+15, all 32 rows (2 MFMA tiles).
template<int MODE, int NC>
static __device__ __forceinline__ void do_layer(
    const uint4* __restrict__ wq,     // per-wave/lane weight base for this layer
    const float* __restrict__ br,     // bias row base (MODE 1)
    float* __restrict__ outg,         // global out (MODE 2)
    unsigned short* xa,
    int wv, int lq, int lr, int n0)
{
    constexpr int PD = 8;             // chunks in flight per wave (8 x 1KB)
    constexpr int RS = PD + 1;        // ring slots: consume slot != issue slot
    constexpr int PA = 2;             // A-fragment (LDS) prefetch depth
    f32x4 acc0 = {0.f,0.f,0.f,0.f}, acc1 = acc0;

    i32x4 ring[RS];
    #pragma unroll
    for (int p = 0; p < PD; ++p)      // prologue: issued before the barrier
        if (p < NC) ring[p % RS] = gload16(wq + p*1024);

    __syncthreads();                  // prior xa writes visible
    const half8* xa8 = (const half8*)xa;
    half8 pa0[PA], pa1[PA];
    #pragma unroll
    for (int p = 0; p < PA; ++p) {
        pa0[p] = xa8[(p*4 + lq)*32 + lr];
        pa1[p] = xa8[(p*4 + lq)*32 + 16 + lr];
    }
    #pragma unroll
    for (int c = 0; c < NC; ++c) {
        if (c + PD < NC)              // issue into slot consumed PD iters ago
            ring[(c+PD) % RS] = gload16(wq + (c+PD)*1024);
        int K = NC-1-c;
        vmwaitK(K > PD ? PD : K, ring[c % RS]);
        half8 b0, a0 = pa0[c % PA], a1 = pa1[c % PA];
        { i32x4 t0 = ring[c % RS]; memcpy(&b0, &t0, 16); }
        if (c + PA < NC) {
            pa0[c % PA] = xa8[((c+PA)*4 + lq)*32 + lr];
            pa1[c % PA] = xa8[((c+PA)*4 + lq)*32 + 16 + lr];
        }
        acc0 = __builtin_amdgcn_mfma_f32_16x16x32_f16(a0, b0, acc0, 0,0,0);
        acc1 = __builtin_amdgcn_mfma_f32_16x16x32_f16(a1, b0, acc1, 0,0,0);
    }
    __syncthreads();                  // all xa reads done
    // ---- epilogue (bias loaded here: keeps K-loop vmcnt exclusively ours) --
    float bb = 0.f;
    if (MODE == 1) bb = br[wv*16 + lr];
    int h = wv*16 + lr;
    #pragma unroll
    for (int rt = 0; rt < 2; ++rt) {
        f32x4 A = rt==0 ? acc0 : acc1;
        #pragma unroll
        for (int r = 0; r < 4; ++r) {
            float v = A[r];
            int m = rt*16 + lq*4 + r;       // C row = quad*4 + reg (m89)
            if (MODE == 2) {
                outg[(size_t)(n0 + m)*256 + h] = v;
            } else if (MODE == 1) {
                float s = sinrev(v + bb);   // weights pre-scaled 1/2pi
                float s3 = s*s*s;
                xa[(((h>>3)     )*32 + m)*8 + (h&7)] = f2h(s);
                xa[(((h>>3) + 32)*32 + m)*8 + (h&7)] = f2h(s3);
            } else {
                xa[((h>>3)*32 + m)*8 + (h&7)] = f2h(v);
            }
        }
    }
}

// ---------------- fused MFMA network kernel --------------------------------
// 1024 threads = 16 waves/CU = 4 waves/SIMD: TLP to absorb L2 latency slop.
// __launch_bounds__(1024, 4) caps VGPR at 128.
__global__ __launch_bounds__(1024, 4)
void net_kernel(const float* __restrict__ coords, const float* __restrict__ Bm,
                const uint4* __restrict__ Wg, const float* __restrict__ b1s,
                float* __restrict__ out)
{
    __shared__ unsigned short xa[64*32*8];    // 32KB activations [kb][m][k%8]
    __shared__ float cb[MT*3];
    __shared__ float bl[384];

    int tid = threadIdx.x, lane = tid & 63, wv = tid >> 6;   // wv 0..15
    int lq = lane >> 4, lr = lane & 15;
    int n0 = blockIdx.x * MT;

    // ---- fourier features + x^3 powers -> xa ----
    if (tid < MT*3) {
        int r = tid/3, d = tid - 3*r, nv = n0 + r;
        cb[tid] = (nv < NCRD) ? coords[nv*6 + d] : coords[(nv-NCRD)*6 + 3 + d];
    }
    if (tid < 384) bl[tid] = Bm[tid];
    __syncthreads();
    {
        int m = tid & 31, cg = tid >> 5;        // col-group 0..31, 8 cols each
        float c0 = cb[m*3], c1 = cb[m*3+1], c2 = cb[m*3+2];
        unsigned short tmp[2][8];
        #pragma unroll
        for (int j = 0; j < 8; ++j) {
            int col = cg*8 + j, f = col & 127;
            float p = c0*bl[f] + c1*bl[128+f] + c2*bl[256+f];   // 2pi cancels
            float s = (col < 128) ? sinrev(p) : cosrev(p);
            tmp[0][j] = f2h(s); tmp[1][j] = f2h(s*s*s);
        }
        #pragma unroll
        for (int pp = 0; pp < 2; ++pp) {
            uint4 v; memcpy(&v, &tmp[pp][0], 16);
            *(uint4*)&xa[((pp*32 + cg)*32 + m)*8] = v;
        }
    }
    // (each do_layer's entry barrier orders xa writes before reads)

    int wl = wv*64 + lane;
    do_layer<0,16>(Wg +      0 + wl, nullptr,   nullptr, xa, wv, lq, lr, n0);
    do_layer<1, 8>(Wg +  16384 + wl, b1s + 0,   nullptr, xa, wv, lq, lr, n0);
    do_layer<0,16>(Wg +  24576 + wl, nullptr,   nullptr, xa, wv, lq, lr, n0);
    do_layer<1, 8>(Wg +  40960 + wl, b1s + 256, nullptr, xa, wv, lq, lr, n0);
    do_layer<0,16>(Wg +  49152 + wl, nullptr,   nullptr, xa, wv, lq, lr, n0);
    do_layer<1, 8>(Wg +  65536 + wl, b1s + 512, nullptr, xa, wv, lq, lr, n0);
    do_layer<0,16>(Wg +  73728 + wl, nullptr,   nullptr, xa, wv, lq, lr, n0);
    do_layer<1, 8>(Wg +  90112 + wl, b1s + 768, nullptr, xa, wv, lq, lr, n0);
    do_layer<2,16>(Wg +  98304 + wl, nullptr,   out,     xa, wv, lq, lr, n0);
}

// ---------------- launch ---------------------------------------------------
extern "C" void kernel_launch(void* const* d_in, const int* in_sizes, int n_in,
                              void* d_out, int out_size, void* d_ws, size_t ws_size,
                              hipStream_t stream)
{
    const float* coords = (const float*)d_in[0];
    const float* Bm     = (const float*)d_in[1];
    const float* w0     = (const float*)d_in[2];
    const float* ws     = (const float*)d_in[3];
    const float* wlast  = (const float*)d_in[4];
    const float* w1     = (const float*)d_in[5];
    const float* b1     = (const float*)d_in[6];
    float* out = (float*)d_out;

    uint4* Wg  = (uint4*)d_ws;                                   // 1.75 MB fp16
    float* b1s = (float*)((char*)d_ws + (size_t)WG_U4*16);       // 4 KB fp32

    dim3 pg(10, 64);
    prep_kernel<<<pg, 256, 0, stream>>>(w0, ws, wlast, w1, coords, b1, Wg, b1s, out);
    net_kernel<<<NROW/MT, 1024, 0, stream>>>(coords, Bm, Wg, b1s, out);
}